// Round 4
// baseline (1311.975 us; speedup 1.0000x reference)
//
#include <hip/hip_runtime.h>

// Problem constants (fixed by the reference)
constexpr int N_  = 100000;
constexpr int E_  = 3200000;
constexpr int FIN = 16;
constexpr int H_  = 128;
constexpr int LAT = 64;
constexpr int L_  = 3;
constexpr int G_  = 1024;

using bf16x8 = __attribute__((ext_vector_type(8))) short;
using f32x4  = __attribute__((ext_vector_type(4))) float;

__device__ inline float bf2f(unsigned int u) {
  union { unsigned int i; float f; } v; v.i = u << 16; return v.f;
}
__device__ inline unsigned short f2bf(float f) {
  union { float f; unsigned int i; } v; v.f = f;
  unsigned int r = v.i + 0x7fffu + ((v.i >> 16) & 1u);   // RNE
  return (unsigned short)(r >> 16);
}

// ---------------------------------------------------------------------------
// One-time: Wt[l][c][k] = bf16(Wmsg[l][k][c])   (transposed for B-fragments)
// ---------------------------------------------------------------------------
__global__ __launch_bounds__(256) void k_wconv(const float* __restrict__ W,
                                               unsigned short* __restrict__ Wt) {
  const int idx = blockIdx.x * 256 + threadIdx.x;      // over 3*128*128
  if (idx < L_ * H_ * H_) {
    const int l = idx >> 14, rem = idx & 16383;
    const int c = rem >> 7, k = rem & 127;
    Wt[idx] = f2bf(W[l * H_ * H_ + k * H_ + c]);
  }
}

// ---------------------------------------------------------------------------
// h = relu(x @ W_in + b_in) -> bf16.  4 nodes/block, lane owns 2 channels.
// ---------------------------------------------------------------------------
__global__ __launch_bounds__(256) void k_input(const float* __restrict__ x,
                                               const float* __restrict__ Win,
                                               const float* __restrict__ bin,
                                               unsigned short* __restrict__ h) {
  __shared__ float Wl[FIN * H_];   // 8 KB
  __shared__ float xl[4 * FIN];
  const int tid = threadIdx.x;
  for (int i = tid; i < FIN * H_; i += 256) Wl[i] = Win[i];
  const int n0 = blockIdx.x * 4;   // N divisible by 4
  if (tid < 4 * FIN) xl[tid] = x[(size_t)n0 * FIN + tid];
  __syncthreads();
  const int nl = tid >> 6, l = tid & 63;
  float a0 = bin[2 * l], a1 = bin[2 * l + 1];
#pragma unroll
  for (int k = 0; k < FIN; ++k) {
    const float xv = xl[nl * FIN + k];
    a0 += xv * Wl[k * H_ + 2 * l];
    a1 += xv * Wl[k * H_ + 2 * l + 1];
  }
  const unsigned int packed =
      (unsigned int)f2bf(fmaxf(a0, 0.f)) | ((unsigned int)f2bf(fmaxf(a1, 0.f)) << 16);
  *reinterpret_cast<unsigned int*>(h + (size_t)(n0 + nl) * H_ + 2 * l) = packed;
}

// ---------------------------------------------------------------------------
// m = h @ W + b  via MFMA (bf16 in, fp32 acc, bf16 out) -> CHUNKED layout
// m8[chunk][node][16ch], chunk = col >> 4.  Block = 4 waves, 32 nodes x 128 cols.
// ---------------------------------------------------------------------------
__global__ __launch_bounds__(256) void k_msg_mfma(const unsigned short* __restrict__ h,
                                                  const unsigned short* __restrict__ Wt,
                                                  const float* __restrict__ b,
                                                  unsigned short* __restrict__ m8) {
  const int wave = threadIdx.x >> 6;
  const int lane = threadIdx.x & 63;
  const int r = lane & 15;
  const int g = lane >> 4;               // 0..3
  const int n0 = blockIdx.x * 32;
  const int cb = wave * 32;

  f32x4 acc[2][2] = {};
#pragma unroll
  for (int kk = 0; kk < 4; ++kk) {
    const int koff = kk * 32 + g * 8;
    const bf16x8 a0 = *reinterpret_cast<const bf16x8*>(h + (size_t)(n0 + r) * H_ + koff);
    const bf16x8 a1 = *reinterpret_cast<const bf16x8*>(h + (size_t)(n0 + 16 + r) * H_ + koff);
    const bf16x8 b0 = *reinterpret_cast<const bf16x8*>(Wt + (size_t)(cb + r) * H_ + koff);
    const bf16x8 b1 = *reinterpret_cast<const bf16x8*>(Wt + (size_t)(cb + 16 + r) * H_ + koff);
    acc[0][0] = __builtin_amdgcn_mfma_f32_16x16x32_bf16(a0, b0, acc[0][0], 0, 0, 0);
    acc[0][1] = __builtin_amdgcn_mfma_f32_16x16x32_bf16(a0, b1, acc[0][1], 0, 0, 0);
    acc[1][0] = __builtin_amdgcn_mfma_f32_16x16x32_bf16(a1, b0, acc[1][0], 0, 0, 0);
    acc[1][1] = __builtin_amdgcn_mfma_f32_16x16x32_bf16(a1, b1, acc[1][1], 0, 0, 0);
  }

  const float bc0 = b[cb + r];
  const float bc1 = b[cb + 16 + r];
#pragma unroll
  for (int rt = 0; rt < 2; ++rt)
#pragma unroll
    for (int ct = 0; ct < 2; ++ct) {
      const float bc = ct ? bc1 : bc0;
      const int chunk = wave * 2 + ct;           // = (cb + ct*16 + r) >> 4
#pragma unroll
      for (int j = 0; j < 4; ++j) {
        const int row = n0 + rt * 16 + g * 4 + j;
        m8[((size_t)chunk * N_ + row) * 16 + r] = f2bf(acc[rt][ct][j] + bc);
      }
    }
}

// ---------------------------------------------------------------------------
// CSR build: counting sort of edges by dst (edge list is layer-invariant).
// ---------------------------------------------------------------------------
__global__ __launch_bounds__(256) void k_hist(const int* __restrict__ ei,
                                              int* __restrict__ deg) {
  const int gid = blockIdx.x * blockDim.x + threadIdx.x;
  const int stride = gridDim.x * blockDim.x;
  for (int e = gid; e < E_; e += stride) atomicAdd(&deg[ei[E_ + e]], 1);
}

__global__ __launch_bounds__(1024) void k_scan(const int* __restrict__ deg,
                                               int* __restrict__ rowptr) {
  __shared__ int sums[1024];
  const int t = threadIdx.x;
  constexpr int CH = (N_ + 1023) / 1024;   // 98
  const int beg = t * CH;
  const int end = min(beg + CH, N_);
  int s = 0;
  for (int i = beg; i < end; ++i) s += deg[i];
  sums[t] = s;
  __syncthreads();
  for (int off = 1; off < 1024; off <<= 1) {
    const int add = (t >= off) ? sums[t - off] : 0;
    __syncthreads();
    sums[t] += add;
    __syncthreads();
  }
  int run = (t == 0) ? 0 : sums[t - 1];
  for (int i = beg; i < end; ++i) { rowptr[i] = run; run += deg[i]; }
  if (beg < N_ && end == N_) rowptr[N_] = run;
}

__global__ __launch_bounds__(256) void k_fill(const int* __restrict__ ei,
                                              const int* __restrict__ rowptr,
                                              int* __restrict__ fill,
                                              int* __restrict__ ssrc) {
  const int gid = blockIdx.x * blockDim.x + threadIdx.x;
  const int stride = gridDim.x * blockDim.x;
  for (int e = gid; e < E_; e += stride) {
    const int src = ei[e];
    const int dst = ei[E_ + e];
    const int pos = rowptr[dst] + atomicAdd(&fill[dst], 1);
    ssrc[pos] = src;
  }
}

// ---------------------------------------------------------------------------
// Chunked gather: h[n][chunk*16+c] = relu( sum_e m8[chunk][ssrc[e]][c] ).
// chunk = blockIdx&7 -> pinned to one XCD (round-robin dispatch) so each
// XCD's L2 only caches its own 3.2 MB slice of m8.
// 4 lanes per (node,chunk): lane s owns channels s*4..s*4+3 (8 B loads).
// 64 nodes per 256-thread block.
// ---------------------------------------------------------------------------
__global__ __launch_bounds__(256) void k_gather8(const unsigned short* __restrict__ m8,
                                                 const int* __restrict__ rowptr,
                                                 const int* __restrict__ ssrc,
                                                 unsigned short* __restrict__ h) {
  const int chunk = blockIdx.x & 7;
  const int nb    = blockIdx.x >> 3;
  const int n     = nb * 64 + (threadIdx.x >> 2);
  const int s     = threadIdx.x & 3;
  if (n >= N_) return;
  const int beg = rowptr[n], end = rowptr[n + 1];
  const unsigned short* mc = m8 + (size_t)chunk * N_ * 16 + s * 4;
  float a0 = 0.f, a1 = 0.f, a2 = 0.f, a3 = 0.f;
  int i = beg;
  for (; i + 1 < end; i += 2) {
    const int s0 = ssrc[i];
    const int s1 = ssrc[i + 1];
    const uint2 v0 = *reinterpret_cast<const uint2*>(mc + (size_t)s0 * 16);
    const uint2 v1 = *reinterpret_cast<const uint2*>(mc + (size_t)s1 * 16);
    a0 += bf2f(v0.x & 0xffffu);  a1 += bf2f(v0.x >> 16);
    a2 += bf2f(v0.y & 0xffffu);  a3 += bf2f(v0.y >> 16);
    a0 += bf2f(v1.x & 0xffffu);  a1 += bf2f(v1.x >> 16);
    a2 += bf2f(v1.y & 0xffffu);  a3 += bf2f(v1.y >> 16);
  }
  if (i < end) {
    const uint2 v = *reinterpret_cast<const uint2*>(mc + (size_t)ssrc[i] * 16);
    a0 += bf2f(v.x & 0xffffu);  a1 += bf2f(v.x >> 16);
    a2 += bf2f(v.y & 0xffffu);  a3 += bf2f(v.y >> 16);
  }
  uint2 o;
  o.x = (unsigned int)f2bf(fmaxf(a0, 0.f)) | ((unsigned int)f2bf(fmaxf(a1, 0.f)) << 16);
  o.y = (unsigned int)f2bf(fmaxf(a2, 0.f)) | ((unsigned int)f2bf(fmaxf(a3, 0.f)) << 16);
  *reinterpret_cast<uint2*>(h + (size_t)n * H_ + chunk * 16 + s * 4) = o;
}

// ---------------------------------------------------------------------------
// ge[g] += h[n] (h already post-relu) with batch sorted: running sum + flush.
// ---------------------------------------------------------------------------
constexpr int POOL_CHUNK = 128;
__global__ __launch_bounds__(128) void k_pool(const unsigned short* __restrict__ h,
                                              const int* __restrict__ batch,
                                              float* __restrict__ ge) {
  __shared__ int bl[POOL_CHUNK];
  const int tid = threadIdx.x;
  const int start = blockIdx.x * POOL_CHUNK;
  const int cnt = min(POOL_CHUNK, N_ - start);
  if (tid < cnt) bl[tid] = batch[start + tid];
  __syncthreads();
  float run = 0.f;
  int cur = bl[0];
  for (int i = 0; i < cnt; ++i) {
    const int bid = bl[i];
    const float v = bf2f((unsigned int)h[(size_t)(start + i) * H_ + tid]);
    if (bid != cur) {
      unsafeAtomicAdd(&ge[(size_t)cur * H_ + tid], run);
      run = 0.f;
      cur = bid;
    }
    run += v;
  }
  unsafeAtomicAdd(&ge[(size_t)cur * H_ + tid], run);
}

// ---------------------------------------------------------------------------
// out = [ge @ W_mean + b_mean ; ge @ W_logvar + b_logvar]
// ---------------------------------------------------------------------------
__global__ __launch_bounds__(128) void k_out(const float* __restrict__ ge,
                                             const float* __restrict__ Wm,
                                             const float* __restrict__ bm,
                                             const float* __restrict__ Wv,
                                             const float* __restrict__ bv,
                                             float* __restrict__ out) {
  __shared__ float gl[H_];
  const int g = blockIdx.x, tid = threadIdx.x;
  gl[tid] = ge[(size_t)g * H_ + tid];
  __syncthreads();
  const bool is_mean = (tid < LAT);
  const float* W = is_mean ? Wm : Wv;
  const float* bb = is_mean ? bm : bv;
  const int c = tid & 63;
  float acc = bb[c];
#pragma unroll 8
  for (int k = 0; k < H_; ++k) acc += gl[k] * W[k * LAT + c];
  const size_t off = is_mean ? 0 : (size_t)G_ * LAT;
  out[off + (size_t)g * LAT + c] = acc;
}

// ---------------------------------------------------------------------------
extern "C" void kernel_launch(void* const* d_in, const int* in_sizes, int n_in,
                              void* d_out, int out_size, void* d_ws, size_t ws_size,
                              hipStream_t stream) {
  const float* x     = (const float*)d_in[0];
  const int*   ei    = (const int*)d_in[1];   // [2,E] int32
  const int*   batch = (const int*)d_in[2];   // [N]  int32 (sorted)
  const float* Win   = (const float*)d_in[4];
  const float* bin   = (const float*)d_in[5];
  const float* Wmsg  = (const float*)d_in[6];
  const float* bmsg  = (const float*)d_in[7];
  const float* Wmean = (const float*)d_in[8];
  const float* bmean = (const float*)d_in[9];
  const float* Wlv   = (const float*)d_in[10];
  const float* blv   = (const float*)d_in[11];
  float* out = (float*)d_out;

  // workspace layout (bytes)
  char* p = (char*)d_ws;
  unsigned short* h  = (unsigned short*)p;  p += (size_t)N_ * H_ * 2;   // 25.6 MB
  unsigned short* m8 = (unsigned short*)p;  p += (size_t)N_ * H_ * 2;   // 25.6 MB chunked
  unsigned short* Wt = (unsigned short*)p;  p += (size_t)L_ * H_ * H_ * 2;
  float* ge          = (float*)p;           p += (size_t)G_ * H_ * 4;
  int* deg           = (int*)p;             p += (size_t)N_ * 4;
  int* rowp          = (int*)p;             p += (size_t)(N_ + 1) * 4;
  int* ssrc          = (int*)p;             // [E]

  // ---- one-time weight convert+transpose ----
  k_wconv<<<(L_ * H_ * H_ + 255) / 256, 256, 0, stream>>>(Wmsg, Wt);

  // ---- CSR build (once; edge list shared by all 3 layers) ----
  hipMemsetAsync(deg, 0, (size_t)N_ * sizeof(int), stream);
  k_hist<<<2048, 256, 0, stream>>>(ei, deg);
  k_scan<<<1, 1024, 0, stream>>>(deg, rowp);
  hipMemsetAsync(deg, 0, (size_t)N_ * sizeof(int), stream);   // reuse as fill cursor
  k_fill<<<2048, 256, 0, stream>>>(ei, rowp, deg, ssrc);

  // ---- h = relu(x @ W_in + b_in) ----
  k_input<<<N_ / 4, 256, 0, stream>>>(x, Win, bin, h);

  const int gblocks = 8 * ((N_ + 63) / 64);   // chunk = blockIdx & 7
  for (int l = 0; l < L_; ++l) {
    k_msg_mfma<<<N_ / 32, 256, 0, stream>>>(h, Wt + (size_t)l * H_ * H_,
                                            bmsg + (size_t)l * H_, m8);
    k_gather8<<<gblocks, 256, 0, stream>>>(m8, rowp, ssrc, h);
  }

  // ---- graph pooling ----
  hipMemsetAsync(ge, 0, (size_t)G_ * H_ * sizeof(float), stream);
  k_pool<<<(N_ + POOL_CHUNK - 1) / POOL_CHUNK, 128, 0, stream>>>(h, batch, ge);

  // ---- heads ----
  k_out<<<G_, 128, 0, stream>>>(ge, Wmean, bmean, Wlv, blv, out);
}

// Round 5
// 770.962 us; speedup vs baseline: 1.7017x; 1.7017x over previous
//
#include <hip/hip_runtime.h>

// Problem constants (fixed by the reference)
constexpr int N_  = 100000;
constexpr int E_  = 3200000;
constexpr int FIN = 16;
constexpr int H_  = 128;
constexpr int LAT = 64;
constexpr int L_  = 3;
constexpr int G_  = 1024;

// CSR bucketing: buckets of 512 nodes
constexpr int BSH = 9;
constexpr int BNODES = 1 << BSH;                    // 512
constexpr int NB_ = (N_ + BNODES - 1) / BNODES;     // 196
constexpr int FILL_NB = 512;
constexpr int FILL_CHUNK = E_ / FILL_NB;            // 6250 (exact)

using bf16x8 = __attribute__((ext_vector_type(8))) short;
using f32x4  = __attribute__((ext_vector_type(4))) float;

__device__ inline float bflo(unsigned int u) {   // low bf16 -> f32
  union { unsigned int i; float f; } v; v.i = u << 16; return v.f;
}
__device__ inline float bfhi(unsigned int u) {   // high bf16 -> f32
  union { unsigned int i; float f; } v; v.i = u & 0xffff0000u; return v.f;
}
__device__ inline unsigned short f2bf(float f) {
  union { float f; unsigned int i; } v; v.f = f;
  unsigned int r = v.i + 0x7fffu + ((v.i >> 16) & 1u);   // RNE
  return (unsigned short)(r >> 16);
}

// ---------------------------------------------------------------------------
// One-time: Wt[l][c][k] = bf16(Wmsg[l][k][c])   (transposed for B-fragments)
// ---------------------------------------------------------------------------
__global__ __launch_bounds__(256) void k_wconv(const float* __restrict__ W,
                                               unsigned short* __restrict__ Wt) {
  const int idx = blockIdx.x * 256 + threadIdx.x;      // over 3*128*128
  if (idx < L_ * H_ * H_) {
    const int l = idx >> 14, rem = idx & 16383;
    const int c = rem >> 7, k = rem & 127;
    Wt[idx] = f2bf(W[l * H_ * H_ + k * H_ + c]);
  }
}

// ---------------------------------------------------------------------------
// h = relu(x @ W_in + b_in) -> bf16.  4 nodes/block, lane owns 2 channels.
// ---------------------------------------------------------------------------
__global__ __launch_bounds__(256) void k_input(const float* __restrict__ x,
                                               const float* __restrict__ Win,
                                               const float* __restrict__ bin,
                                               unsigned short* __restrict__ h) {
  __shared__ float Wl[FIN * H_];   // 8 KB
  __shared__ float xl[4 * FIN];
  const int tid = threadIdx.x;
  for (int i = tid; i < FIN * H_; i += 256) Wl[i] = Win[i];
  const int n0 = blockIdx.x * 4;   // N divisible by 4
  if (tid < 4 * FIN) xl[tid] = x[(size_t)n0 * FIN + tid];
  __syncthreads();
  const int nl = tid >> 6, l = tid & 63;
  float a0 = bin[2 * l], a1 = bin[2 * l + 1];
#pragma unroll
  for (int k = 0; k < FIN; ++k) {
    const float xv = xl[nl * FIN + k];
    a0 += xv * Wl[k * H_ + 2 * l];
    a1 += xv * Wl[k * H_ + 2 * l + 1];
  }
  const unsigned int packed =
      (unsigned int)f2bf(fmaxf(a0, 0.f)) | ((unsigned int)f2bf(fmaxf(a1, 0.f)) << 16);
  *reinterpret_cast<unsigned int*>(h + (size_t)(n0 + nl) * H_ + 2 * l) = packed;
}

// ---------------------------------------------------------------------------
// m = h @ W + b  via MFMA (bf16 in, fp32 acc, bf16 out).  [N][H] layout.
// Block = 4 waves, tile 32 nodes x 128 cols.
// ---------------------------------------------------------------------------
__global__ __launch_bounds__(256) void k_msg_mfma(const unsigned short* __restrict__ h,
                                                  const unsigned short* __restrict__ Wt,
                                                  const float* __restrict__ b,
                                                  unsigned short* __restrict__ m) {
  const int wave = threadIdx.x >> 6;
  const int lane = threadIdx.x & 63;
  const int r = lane & 15;
  const int g = lane >> 4;               // 0..3
  const int n0 = blockIdx.x * 32;
  const int cb = wave * 32;

  f32x4 acc[2][2] = {};
#pragma unroll
  for (int kk = 0; kk < 4; ++kk) {
    const int koff = kk * 32 + g * 8;
    const bf16x8 a0 = *reinterpret_cast<const bf16x8*>(h + (size_t)(n0 + r) * H_ + koff);
    const bf16x8 a1 = *reinterpret_cast<const bf16x8*>(h + (size_t)(n0 + 16 + r) * H_ + koff);
    const bf16x8 b0 = *reinterpret_cast<const bf16x8*>(Wt + (size_t)(cb + r) * H_ + koff);
    const bf16x8 b1 = *reinterpret_cast<const bf16x8*>(Wt + (size_t)(cb + 16 + r) * H_ + koff);
    acc[0][0] = __builtin_amdgcn_mfma_f32_16x16x32_bf16(a0, b0, acc[0][0], 0, 0, 0);
    acc[0][1] = __builtin_amdgcn_mfma_f32_16x16x32_bf16(a0, b1, acc[0][1], 0, 0, 0);
    acc[1][0] = __builtin_amdgcn_mfma_f32_16x16x32_bf16(a1, b0, acc[1][0], 0, 0, 0);
    acc[1][1] = __builtin_amdgcn_mfma_f32_16x16x32_bf16(a1, b1, acc[1][1], 0, 0, 0);
  }

  const float bc0 = b[cb + r];
  const float bc1 = b[cb + 16 + r];
#pragma unroll
  for (int rt = 0; rt < 2; ++rt)
#pragma unroll
    for (int ct = 0; ct < 2; ++ct) {
      const float bc = ct ? bc1 : bc0;
      const int col = cb + ct * 16 + r;
#pragma unroll
      for (int j = 0; j < 4; ++j) {
        const int row = n0 + rt * 16 + g * 4 + j;
        m[(size_t)row * H_ + col] = f2bf(acc[rt][ct][j] + bc);
      }
    }
}

// ---------------------------------------------------------------------------
// Bucketed CSR build (line-friendly counting sort, 4 small kernels)
// ---------------------------------------------------------------------------
// 1) global bucket histogram (LDS-staged)
__global__ __launch_bounds__(256) void k_bhist(const int* __restrict__ ei,
                                               int* __restrict__ bcnt) {
  __shared__ int lh[NB_];
  for (int i = threadIdx.x; i < NB_; i += 256) lh[i] = 0;
  __syncthreads();
  const int gid = blockIdx.x * 256 + threadIdx.x;
  const int stride = gridDim.x * 256;
  for (int e = gid; e < E_; e += stride) atomicAdd(&lh[ei[E_ + e] >> BSH], 1);
  __syncthreads();
  for (int i = threadIdx.x; i < NB_; i += 256)
    if (lh[i]) atomicAdd(&bcnt[i], lh[i]);
}

// 2) scan 196 buckets -> boff[NB+1], init bcur
__global__ __launch_bounds__(256) void k_bscan(const int* __restrict__ bcnt,
                                               int* __restrict__ boff,
                                               int* __restrict__ bcur) {
  __shared__ int s[256];
  const int t = threadIdx.x;
  s[t] = (t < NB_) ? bcnt[t] : 0;
  __syncthreads();
  for (int off = 1; off < 256; off <<= 1) {
    const int add = (t >= off) ? s[t - off] : 0;
    __syncthreads();
    s[t] += add;
    __syncthreads();
  }
  const int ex = (t == 0) ? 0 : s[t - 1];
  if (t < NB_) { boff[t] = ex; bcur[t] = ex; }
  if (t == 0) boff[NB_] = s[NB_ - 1];   // == E
}

// 3) partition edges into bucket-contiguous regions; per-block reservations
//    keep writes line-local (~32 edges = 256 B per block-bucket region).
__global__ __launch_bounds__(256) void k_bfill(const int* __restrict__ ei,
                                               int* __restrict__ bcur,
                                               uint2* __restrict__ ebuf) {
  __shared__ int lh[NB_], lbase[NB_];
  const int t = threadIdx.x;
  for (int i = t; i < NB_; i += 256) lh[i] = 0;
  __syncthreads();
  const int e0 = blockIdx.x * FILL_CHUNK;
  const int e1 = e0 + FILL_CHUNK;
  for (int e = e0 + t; e < e1; e += 256) atomicAdd(&lh[ei[E_ + e] >> BSH], 1);
  __syncthreads();
  for (int i = t; i < NB_; i += 256) {
    const int c = lh[i];
    lbase[i] = c ? atomicAdd(&bcur[i], c) : 0;
  }
  __syncthreads();
  for (int i = t; i < NB_; i += 256) lh[i] = 0;   // reuse as local cursor
  __syncthreads();
  for (int e = e0 + t; e < e1; e += 256) {
    const int src = ei[e], dst = ei[E_ + e];
    const int b = dst >> BSH;
    const int pos = lbase[b] + atomicAdd(&lh[b], 1);
    ebuf[pos] = make_uint2((unsigned)src, (unsigned)dst);
  }
}

// 4) per-bucket local CSR: one block per bucket; hist+scan+scatter in LDS,
//    ssrc writes confined to the bucket's private ~65 KB window.
__global__ __launch_bounds__(256) void k_bcsr(const uint2* __restrict__ ebuf,
                                              const int* __restrict__ boff,
                                              int* __restrict__ rowp,
                                              int* __restrict__ ssrc) {
  __shared__ int sdeg[BNODES];
  __shared__ int scur[BNODES];
  __shared__ int part[256];
  const int b = blockIdx.x;
  const int nbase = b << BSH;
  const int ncnt = min(BNODES, N_ - nbase);
  const int ebeg = boff[b], eend = boff[b + 1];
  const int t = threadIdx.x;
  for (int i = t; i < BNODES; i += 256) { sdeg[i] = 0; scur[i] = 0; }
  __syncthreads();
  for (int e = ebeg + t; e < eend; e += 256)
    atomicAdd(&sdeg[(int)ebuf[e].y - nbase], 1);
  __syncthreads();
  // exclusive scan of sdeg[0..512) with 256 threads (2 elems each)
  const int i0 = 2 * t, i1 = 2 * t + 1;
  const int d0 = sdeg[i0];
  part[t] = d0 + sdeg[i1];
  __syncthreads();
  for (int off = 1; off < 256; off <<= 1) {
    const int add = (t >= off) ? part[t - off] : 0;
    __syncthreads();
    part[t] += add;
    __syncthreads();
  }
  const int ex = (t == 0) ? 0 : part[t - 1];
  sdeg[i0] = ex;
  sdeg[i1] = ex + d0;
  __syncthreads();
  for (int i = t; i < ncnt; i += 256) rowp[nbase + i] = ebeg + sdeg[i];
  if (b == NB_ - 1 && t == 0) rowp[N_] = E_;
  for (int e = ebeg + t; e < eend; e += 256) {
    const uint2 ed = ebuf[e];
    const int ld = (int)ed.y - nbase;
    const int pos = ebeg + sdeg[ld] + atomicAdd(&scur[ld], 1);
    ssrc[pos] = (int)ed.x;
  }
}

// ---------------------------------------------------------------------------
// h[n] = relu( sum_{e in CSR[n]} m[ssrc[e]] )  bf16 rows, fp32 accum.
// 64 lanes per node (2 channels each), 4 nodes per 256-thread block.
// ---------------------------------------------------------------------------
__global__ __launch_bounds__(256) void k_gather(const unsigned short* __restrict__ m,
                                                const int* __restrict__ rowptr,
                                                const int* __restrict__ ssrc,
                                                unsigned short* __restrict__ h) {
  const int n = blockIdx.x * 4 + (threadIdx.x >> 6);
  const int c2 = threadIdx.x & 63;          // channel pair -> channels 2c2, 2c2+1
  const int beg = rowptr[n], end = rowptr[n + 1];
  float a0 = 0.f, a1 = 0.f;
  int i = beg;
  for (; i + 1 < end; i += 2) {
    const int s0 = ssrc[i];
    const int s1 = ssrc[i + 1];
    const unsigned int v0 = *reinterpret_cast<const unsigned int*>(m + (size_t)s0 * H_ + 2 * c2);
    const unsigned int v1 = *reinterpret_cast<const unsigned int*>(m + (size_t)s1 * H_ + 2 * c2);
    a0 += bflo(v0);  a1 += bfhi(v0);
    a0 += bflo(v1);  a1 += bfhi(v1);
  }
  if (i < end) {
    const unsigned int v = *reinterpret_cast<const unsigned int*>(m + (size_t)ssrc[i] * H_ + 2 * c2);
    a0 += bflo(v);  a1 += bfhi(v);
  }
  const unsigned int packed =
      (unsigned int)f2bf(fmaxf(a0, 0.f)) | ((unsigned int)f2bf(fmaxf(a1, 0.f)) << 16);
  *reinterpret_cast<unsigned int*>(h + (size_t)n * H_ + 2 * c2) = packed;
}

// ---------------------------------------------------------------------------
// ge[g] += h[n] (h already post-relu) with batch sorted: running sum + flush.
// ---------------------------------------------------------------------------
constexpr int POOL_CHUNK = 128;
__global__ __launch_bounds__(128) void k_pool(const unsigned short* __restrict__ h,
                                              const int* __restrict__ batch,
                                              float* __restrict__ ge) {
  __shared__ int bl[POOL_CHUNK];
  const int tid = threadIdx.x;
  const int start = blockIdx.x * POOL_CHUNK;
  const int cnt = min(POOL_CHUNK, N_ - start);
  if (tid < cnt) bl[tid] = batch[start + tid];
  __syncthreads();
  float run = 0.f;
  int cur = bl[0];
  for (int i = 0; i < cnt; ++i) {
    const int bid = bl[i];
    const float v = bflo((unsigned int)h[(size_t)(start + i) * H_ + tid]);
    if (bid != cur) {
      unsafeAtomicAdd(&ge[(size_t)cur * H_ + tid], run);
      run = 0.f;
      cur = bid;
    }
    run += v;
  }
  unsafeAtomicAdd(&ge[(size_t)cur * H_ + tid], run);
}

// ---------------------------------------------------------------------------
// out = [ge @ W_mean + b_mean ; ge @ W_logvar + b_logvar]
// ---------------------------------------------------------------------------
__global__ __launch_bounds__(128) void k_out(const float* __restrict__ ge,
                                             const float* __restrict__ Wm,
                                             const float* __restrict__ bm,
                                             const float* __restrict__ Wv,
                                             const float* __restrict__ bv,
                                             float* __restrict__ out) {
  __shared__ float gl[H_];
  const int g = blockIdx.x, tid = threadIdx.x;
  gl[tid] = ge[(size_t)g * H_ + tid];
  __syncthreads();
  const bool is_mean = (tid < LAT);
  const float* W = is_mean ? Wm : Wv;
  const float* bb = is_mean ? bm : bv;
  const int c = tid & 63;
  float acc = bb[c];
#pragma unroll 8
  for (int k = 0; k < H_; ++k) acc += gl[k] * W[k * LAT + c];
  const size_t off = is_mean ? 0 : (size_t)G_ * LAT;
  out[off + (size_t)g * LAT + c] = acc;
}

// ---------------------------------------------------------------------------
extern "C" void kernel_launch(void* const* d_in, const int* in_sizes, int n_in,
                              void* d_out, int out_size, void* d_ws, size_t ws_size,
                              hipStream_t stream) {
  const float* x     = (const float*)d_in[0];
  const int*   ei    = (const int*)d_in[1];   // [2,E] int32
  const int*   batch = (const int*)d_in[2];   // [N]  int32 (sorted)
  const float* Win   = (const float*)d_in[4];
  const float* bin   = (const float*)d_in[5];
  const float* Wmsg  = (const float*)d_in[6];
  const float* bmsg  = (const float*)d_in[7];
  const float* Wmean = (const float*)d_in[8];
  const float* bmean = (const float*)d_in[9];
  const float* Wlv   = (const float*)d_in[10];
  const float* blv   = (const float*)d_in[11];
  float* out = (float*)d_out;

  // workspace layout (bytes), large-first for alignment
  char* p = (char*)d_ws;
  unsigned short* h  = (unsigned short*)p;  p += (size_t)N_ * H_ * 2;   // 25.6 MB
  unsigned short* m  = (unsigned short*)p;  p += (size_t)N_ * H_ * 2;   // 25.6 MB
  uint2* ebuf        = (uint2*)p;           p += (size_t)E_ * 8;        // 25.6 MB
  int* ssrc          = (int*)p;             p += (size_t)E_ * 4;        // 12.8 MB
  int* rowp          = (int*)p;             p += (size_t)(N_ + 1) * 4;
  unsigned short* Wt = (unsigned short*)p;  p += (size_t)L_ * H_ * H_ * 2;
  float* ge          = (float*)p;           p += (size_t)G_ * H_ * 4;
  int* bcnt          = (int*)p;             p += (size_t)NB_ * 4;
  int* boff          = (int*)p;             p += (size_t)(NB_ + 1) * 4;
  int* bcur          = (int*)p;             p += (size_t)NB_ * 4;

  // ---- one-time weight convert+transpose ----
  k_wconv<<<(L_ * H_ * H_ + 255) / 256, 256, 0, stream>>>(Wmsg, Wt);

  // ---- bucketed CSR build (once; edge list shared by all 3 layers) ----
  hipMemsetAsync(bcnt, 0, (size_t)NB_ * sizeof(int), stream);
  k_bhist<<<256, 256, 0, stream>>>(ei, bcnt);
  k_bscan<<<1, 256, 0, stream>>>(bcnt, boff, bcur);
  k_bfill<<<FILL_NB, 256, 0, stream>>>(ei, bcur, ebuf);
  k_bcsr<<<NB_, 256, 0, stream>>>(ebuf, boff, rowp, ssrc);

  // ---- h = relu(x @ W_in + b_in) ----
  k_input<<<N_ / 4, 256, 0, stream>>>(x, Win, bin, h);

  for (int l = 0; l < L_; ++l) {
    k_msg_mfma<<<N_ / 32, 256, 0, stream>>>(h, Wt + (size_t)l * H_ * H_,
                                            bmsg + (size_t)l * H_, m);
    k_gather<<<N_ / 4, 256, 0, stream>>>(m, rowp, ssrc, h);
  }

  // ---- graph pooling ----
  hipMemsetAsync(ge, 0, (size_t)G_ * H_ * sizeof(float), stream);
  k_pool<<<(N_ + POOL_CHUNK - 1) / POOL_CHUNK, 128, 0, stream>>>(h, batch, ge);

  // ---- heads ----
  k_out<<<G_, 128, 0, stream>>>(ge, Wmean, bmean, Wlv, blv, out);
}

// Round 6
// 609.261 us; speedup vs baseline: 2.1534x; 1.2654x over previous
//
#include <hip/hip_runtime.h>

// Problem constants (fixed by the reference)
constexpr int N_  = 100000;
constexpr int E_  = 3200000;
constexpr int FIN = 16;
constexpr int H_  = 128;
constexpr int LAT = 64;
constexpr int L_  = 3;
constexpr int G_  = 1024;

// CSR bucketing: buckets of 512 nodes
constexpr int BSH = 9;
constexpr int BNODES = 1 << BSH;                    // 512
constexpr int NB_ = (N_ + BNODES - 1) / BNODES;     // 196
constexpr int FILL_NB = 512;
constexpr int FILL_CHUNK = E_ / FILL_NB;            // 6250 (exact)

using bf16x8 = __attribute__((ext_vector_type(8))) short;
using f32x4  = __attribute__((ext_vector_type(4))) float;

__device__ inline float bflo(unsigned int u) {   // low bf16 -> f32
  union { unsigned int i; float f; } v; v.i = u << 16; return v.f;
}
__device__ inline float bfhi(unsigned int u) {   // high bf16 -> f32
  union { unsigned int i; float f; } v; v.i = u & 0xffff0000u; return v.f;
}
__device__ inline unsigned short f2bf(float f) {
  union { float f; unsigned int i; } v; v.f = f;
  unsigned int r = v.i + 0x7fffu + ((v.i >> 16) & 1u);   // RNE
  return (unsigned short)(r >> 16);
}

// ---------------------------------------------------------------------------
// One-time: Wt[l][c][k] = bf16(Wmsg[l][k][c])   (transposed for B-fragments)
// ---------------------------------------------------------------------------
__global__ __launch_bounds__(256) void k_wconv(const float* __restrict__ W,
                                               unsigned short* __restrict__ Wt) {
  const int idx = blockIdx.x * 256 + threadIdx.x;      // over 3*128*128
  if (idx < L_ * H_ * H_) {
    const int l = idx >> 14, rem = idx & 16383;
    const int c = rem >> 7, k = rem & 127;
    Wt[idx] = f2bf(W[l * H_ * H_ + k * H_ + c]);
  }
}

// ---------------------------------------------------------------------------
// h = relu(x @ W_in + b_in) -> bf16.  4 nodes/block, lane owns 2 channels.
// ---------------------------------------------------------------------------
__global__ __launch_bounds__(256) void k_input(const float* __restrict__ x,
                                               const float* __restrict__ Win,
                                               const float* __restrict__ bin,
                                               unsigned short* __restrict__ h) {
  __shared__ float Wl[FIN * H_];   // 8 KB
  __shared__ float xl[4 * FIN];
  const int tid = threadIdx.x;
  for (int i = tid; i < FIN * H_; i += 256) Wl[i] = Win[i];
  const int n0 = blockIdx.x * 4;   // N divisible by 4
  if (tid < 4 * FIN) xl[tid] = x[(size_t)n0 * FIN + tid];
  __syncthreads();
  const int nl = tid >> 6, l = tid & 63;
  float a0 = bin[2 * l], a1 = bin[2 * l + 1];
#pragma unroll
  for (int k = 0; k < FIN; ++k) {
    const float xv = xl[nl * FIN + k];
    a0 += xv * Wl[k * H_ + 2 * l];
    a1 += xv * Wl[k * H_ + 2 * l + 1];
  }
  const unsigned int packed =
      (unsigned int)f2bf(fmaxf(a0, 0.f)) | ((unsigned int)f2bf(fmaxf(a1, 0.f)) << 16);
  *reinterpret_cast<unsigned int*>(h + (size_t)(n0 + nl) * H_ + 2 * l) = packed;
}

// ---------------------------------------------------------------------------
// m = h @ W + b  via MFMA (bf16 in, fp32 acc, bf16 out).  [N][H] layout.
// Block = 4 waves, tile 32 nodes x 128 cols.
// ---------------------------------------------------------------------------
__global__ __launch_bounds__(256) void k_msg_mfma(const unsigned short* __restrict__ h,
                                                  const unsigned short* __restrict__ Wt,
                                                  const float* __restrict__ b,
                                                  unsigned short* __restrict__ m) {
  const int wave = threadIdx.x >> 6;
  const int lane = threadIdx.x & 63;
  const int r = lane & 15;
  const int g = lane >> 4;               // 0..3
  const int n0 = blockIdx.x * 32;
  const int cb = wave * 32;

  f32x4 acc[2][2] = {};
#pragma unroll
  for (int kk = 0; kk < 4; ++kk) {
    const int koff = kk * 32 + g * 8;
    const bf16x8 a0 = *reinterpret_cast<const bf16x8*>(h + (size_t)(n0 + r) * H_ + koff);
    const bf16x8 a1 = *reinterpret_cast<const bf16x8*>(h + (size_t)(n0 + 16 + r) * H_ + koff);
    const bf16x8 b0 = *reinterpret_cast<const bf16x8*>(Wt + (size_t)(cb + r) * H_ + koff);
    const bf16x8 b1 = *reinterpret_cast<const bf16x8*>(Wt + (size_t)(cb + 16 + r) * H_ + koff);
    acc[0][0] = __builtin_amdgcn_mfma_f32_16x16x32_bf16(a0, b0, acc[0][0], 0, 0, 0);
    acc[0][1] = __builtin_amdgcn_mfma_f32_16x16x32_bf16(a0, b1, acc[0][1], 0, 0, 0);
    acc[1][0] = __builtin_amdgcn_mfma_f32_16x16x32_bf16(a1, b0, acc[1][0], 0, 0, 0);
    acc[1][1] = __builtin_amdgcn_mfma_f32_16x16x32_bf16(a1, b1, acc[1][1], 0, 0, 0);
  }

  const float bc0 = b[cb + r];
  const float bc1 = b[cb + 16 + r];
#pragma unroll
  for (int rt = 0; rt < 2; ++rt)
#pragma unroll
    for (int ct = 0; ct < 2; ++ct) {
      const float bc = ct ? bc1 : bc0;
      const int col = cb + ct * 16 + r;
#pragma unroll
      for (int j = 0; j < 4; ++j) {
        const int row = n0 + rt * 16 + g * 4 + j;
        m[(size_t)row * H_ + col] = f2bf(acc[rt][ct][j] + bc);
      }
    }
}

// ---------------------------------------------------------------------------
// Bucketed CSR build (line-friendly counting sort, 4 small kernels)
// ---------------------------------------------------------------------------
__global__ __launch_bounds__(256) void k_bhist(const int* __restrict__ ei,
                                               int* __restrict__ bcnt) {
  __shared__ int lh[NB_];
  for (int i = threadIdx.x; i < NB_; i += 256) lh[i] = 0;
  __syncthreads();
  const int gid = blockIdx.x * 256 + threadIdx.x;
  const int stride = gridDim.x * 256;
  for (int e = gid; e < E_; e += stride) atomicAdd(&lh[ei[E_ + e] >> BSH], 1);
  __syncthreads();
  for (int i = threadIdx.x; i < NB_; i += 256)
    if (lh[i]) atomicAdd(&bcnt[i], lh[i]);
}

__global__ __launch_bounds__(256) void k_bscan(const int* __restrict__ bcnt,
                                               int* __restrict__ boff,
                                               int* __restrict__ bcur) {
  __shared__ int s[256];
  const int t = threadIdx.x;
  s[t] = (t < NB_) ? bcnt[t] : 0;
  __syncthreads();
  for (int off = 1; off < 256; off <<= 1) {
    const int add = (t >= off) ? s[t - off] : 0;
    __syncthreads();
    s[t] += add;
    __syncthreads();
  }
  const int ex = (t == 0) ? 0 : s[t - 1];
  if (t < NB_) { boff[t] = ex; bcur[t] = ex; }
  if (t == 0) boff[NB_] = s[NB_ - 1];   // == E
}

__global__ __launch_bounds__(256) void k_bfill(const int* __restrict__ ei,
                                               int* __restrict__ bcur,
                                               uint2* __restrict__ ebuf) {
  __shared__ int lh[NB_], lbase[NB_];
  const int t = threadIdx.x;
  for (int i = t; i < NB_; i += 256) lh[i] = 0;
  __syncthreads();
  const int e0 = blockIdx.x * FILL_CHUNK;
  const int e1 = e0 + FILL_CHUNK;
  for (int e = e0 + t; e < e1; e += 256) atomicAdd(&lh[ei[E_ + e] >> BSH], 1);
  __syncthreads();
  for (int i = t; i < NB_; i += 256) {
    const int c = lh[i];
    lbase[i] = c ? atomicAdd(&bcur[i], c) : 0;
  }
  __syncthreads();
  for (int i = t; i < NB_; i += 256) lh[i] = 0;   // reuse as local cursor
  __syncthreads();
  for (int e = e0 + t; e < e1; e += 256) {
    const int src = ei[e], dst = ei[E_ + e];
    const int b = dst >> BSH;
    const int pos = lbase[b] + atomicAdd(&lh[b], 1);
    ebuf[pos] = make_uint2((unsigned)src, (unsigned)dst);
  }
}

__global__ __launch_bounds__(256) void k_bcsr(const uint2* __restrict__ ebuf,
                                              const int* __restrict__ boff,
                                              int* __restrict__ rowp,
                                              int* __restrict__ ssrc) {
  __shared__ int sdeg[BNODES];
  __shared__ int scur[BNODES];
  __shared__ int part[256];
  const int b = blockIdx.x;
  const int nbase = b << BSH;
  const int ncnt = min(BNODES, N_ - nbase);
  const int ebeg = boff[b], eend = boff[b + 1];
  const int t = threadIdx.x;
  for (int i = t; i < BNODES; i += 256) { sdeg[i] = 0; scur[i] = 0; }
  __syncthreads();
  for (int e = ebeg + t; e < eend; e += 256)
    atomicAdd(&sdeg[(int)ebuf[e].y - nbase], 1);
  __syncthreads();
  // exclusive scan of sdeg[0..512) with 256 threads (2 elems each)
  const int i0 = 2 * t, i1 = 2 * t + 1;
  const int d0 = sdeg[i0];
  part[t] = d0 + sdeg[i1];
  __syncthreads();
  for (int off = 1; off < 256; off <<= 1) {
    const int add = (t >= off) ? part[t - off] : 0;
    __syncthreads();
    part[t] += add;
    __syncthreads();
  }
  const int ex = (t == 0) ? 0 : part[t - 1];
  sdeg[i0] = ex;
  sdeg[i1] = ex + d0;
  __syncthreads();
  for (int i = t; i < ncnt; i += 256) rowp[nbase + i] = ebeg + sdeg[i];
  if (b == NB_ - 1 && t == 0) rowp[N_] = E_;
  for (int e = ebeg + t; e < eend; e += 256) {
    const uint2 ed = ebuf[e];
    const int ld = (int)ed.y - nbase;
    const int pos = ebeg + sdeg[ld] + atomicAdd(&scur[ld], 1);
    ssrc[pos] = (int)ed.x;
  }
}

// ---------------------------------------------------------------------------
// h[n] = relu( sum_{e in CSR[n]} m[ssrc[e]] )  bf16 rows, fp32 accum.
// 64 lanes per node (2 channels each), 4 nodes per 256-thread block.
// UNROLL 4: 4 outstanding 256 B row-loads per wave (latency hiding).
// ---------------------------------------------------------------------------
__global__ __launch_bounds__(256) void k_gather(const unsigned short* __restrict__ m,
                                                const int* __restrict__ rowptr,
                                                const int* __restrict__ ssrc,
                                                unsigned short* __restrict__ h) {
  const int n = blockIdx.x * 4 + (threadIdx.x >> 6);
  const int c2 = threadIdx.x & 63;          // channel pair -> channels 2c2, 2c2+1
  const int beg = rowptr[n], end = rowptr[n + 1];
  const unsigned short* mc = m + 2 * c2;
  float a0 = 0.f, a1 = 0.f;
  int i = beg;
  for (; i + 3 < end; i += 4) {
    const int s0 = ssrc[i];
    const int s1 = ssrc[i + 1];
    const int s2 = ssrc[i + 2];
    const int s3 = ssrc[i + 3];
    const unsigned int v0 = *reinterpret_cast<const unsigned int*>(mc + (size_t)s0 * H_);
    const unsigned int v1 = *reinterpret_cast<const unsigned int*>(mc + (size_t)s1 * H_);
    const unsigned int v2 = *reinterpret_cast<const unsigned int*>(mc + (size_t)s2 * H_);
    const unsigned int v3 = *reinterpret_cast<const unsigned int*>(mc + (size_t)s3 * H_);
    a0 += bflo(v0);  a1 += bfhi(v0);
    a0 += bflo(v1);  a1 += bfhi(v1);
    a0 += bflo(v2);  a1 += bfhi(v2);
    a0 += bflo(v3);  a1 += bfhi(v3);
  }
  for (; i < end; ++i) {
    const unsigned int v = *reinterpret_cast<const unsigned int*>(mc + (size_t)ssrc[i] * H_);
    a0 += bflo(v);  a1 += bfhi(v);
  }
  const unsigned int packed =
      (unsigned int)f2bf(fmaxf(a0, 0.f)) | ((unsigned int)f2bf(fmaxf(a1, 0.f)) << 16);
  *reinterpret_cast<unsigned int*>(h + (size_t)n * H_ + 2 * c2) = packed;
}

// ---------------------------------------------------------------------------
// ge[g] += h[n] (h already post-relu) with batch sorted: running sum + flush.
// ---------------------------------------------------------------------------
constexpr int POOL_CHUNK = 128;
__global__ __launch_bounds__(128) void k_pool(const unsigned short* __restrict__ h,
                                              const int* __restrict__ batch,
                                              float* __restrict__ ge) {
  __shared__ int bl[POOL_CHUNK];
  const int tid = threadIdx.x;
  const int start = blockIdx.x * POOL_CHUNK;
  const int cnt = min(POOL_CHUNK, N_ - start);
  if (tid < cnt) bl[tid] = batch[start + tid];
  __syncthreads();
  float run = 0.f;
  int cur = bl[0];
  for (int i = 0; i < cnt; ++i) {
    const int bid = bl[i];
    const float v = bflo((unsigned int)h[(size_t)(start + i) * H_ + tid]);
    if (bid != cur) {
      unsafeAtomicAdd(&ge[(size_t)cur * H_ + tid], run);
      run = 0.f;
      cur = bid;
    }
    run += v;
  }
  unsafeAtomicAdd(&ge[(size_t)cur * H_ + tid], run);
}

// ---------------------------------------------------------------------------
// out = [ge @ W_mean + b_mean ; ge @ W_logvar + b_logvar]
// ---------------------------------------------------------------------------
__global__ __launch_bounds__(128) void k_out(const float* __restrict__ ge,
                                             const float* __restrict__ Wm,
                                             const float* __restrict__ bm,
                                             const float* __restrict__ Wv,
                                             const float* __restrict__ bv,
                                             float* __restrict__ out) {
  __shared__ float gl[H_];
  const int g = blockIdx.x, tid = threadIdx.x;
  gl[tid] = ge[(size_t)g * H_ + tid];
  __syncthreads();
  const bool is_mean = (tid < LAT);
  const float* W = is_mean ? Wm : Wv;
  const float* bb = is_mean ? bm : bv;
  const int c = tid & 63;
  float acc = bb[c];
#pragma unroll 8
  for (int k = 0; k < H_; ++k) acc += gl[k] * W[k * LAT + c];
  const size_t off = is_mean ? 0 : (size_t)G_ * LAT;
  out[off + (size_t)g * LAT + c] = acc;
}

// ---------------------------------------------------------------------------
extern "C" void kernel_launch(void* const* d_in, const int* in_sizes, int n_in,
                              void* d_out, int out_size, void* d_ws, size_t ws_size,
                              hipStream_t stream) {
  const float* x     = (const float*)d_in[0];
  const int*   ei    = (const int*)d_in[1];   // [2,E] int32
  const int*   batch = (const int*)d_in[2];   // [N]  int32 (sorted)
  const float* Win   = (const float*)d_in[4];
  const float* bin   = (const float*)d_in[5];
  const float* Wmsg  = (const float*)d_in[6];
  const float* bmsg  = (const float*)d_in[7];
  const float* Wmean = (const float*)d_in[8];
  const float* bmean = (const float*)d_in[9];
  const float* Wlv   = (const float*)d_in[10];
  const float* blv   = (const float*)d_in[11];
  float* out = (float*)d_out;

  // workspace layout (bytes), large-first for alignment
  char* p = (char*)d_ws;
  unsigned short* h  = (unsigned short*)p;  p += (size_t)N_ * H_ * 2;   // 25.6 MB
  unsigned short* m  = (unsigned short*)p;  p += (size_t)N_ * H_ * 2;   // 25.6 MB
  uint2* ebuf        = (uint2*)p;           p += (size_t)E_ * 8;        // 25.6 MB
  int* ssrc          = (int*)p;             p += (size_t)E_ * 4;        // 12.8 MB
  int* rowp          = (int*)p;             p += (size_t)(N_ + 1) * 4;
  unsigned short* Wt = (unsigned short*)p;  p += (size_t)L_ * H_ * H_ * 2;
  float* ge          = (float*)p;           p += (size_t)G_ * H_ * 4;
  int* bcnt          = (int*)p;             p += (size_t)NB_ * 4;
  int* boff          = (int*)p;             p += (size_t)(NB_ + 1) * 4;
  int* bcur          = (int*)p;             p += (size_t)NB_ * 4;

  // ---- one-time weight convert+transpose ----
  k_wconv<<<(L_ * H_ * H_ + 255) / 256, 256, 0, stream>>>(Wmsg, Wt);

  // ---- bucketed CSR build (once; edge list shared by all 3 layers) ----
  hipMemsetAsync(bcnt, 0, (size_t)NB_ * sizeof(int), stream);
  k_bhist<<<256, 256, 0, stream>>>(ei, bcnt);
  k_bscan<<<1, 256, 0, stream>>>(bcnt, boff, bcur);
  k_bfill<<<FILL_NB, 256, 0, stream>>>(ei, bcur, ebuf);
  k_bcsr<<<NB_, 256, 0, stream>>>(ebuf, boff, rowp, ssrc);

  // ---- h = relu(x @ W_in + b_in) ----
  k_input<<<N_ / 4, 256, 0, stream>>>(x, Win, bin, h);

  for (int l = 0; l < L_; ++l) {
    k_msg_mfma<<<N_ / 32, 256, 0, stream>>>(h, Wt + (size_t)l * H_ * H_,
                                            bmsg + (size_t)l * H_, m);
    k_gather<<<N_ / 4, 256, 0, stream>>>(m, rowp, ssrc, h);
  }

  // ---- graph pooling ----
  hipMemsetAsync(ge, 0, (size_t)G_ * H_ * sizeof(float), stream);
  k_pool<<<(N_ + POOL_CHUNK - 1) / POOL_CHUNK, 128, 0, stream>>>(h, batch, ge);

  // ---- heads ----
  k_out<<<G_, 128, 0, stream>>>(ge, Wmean, bmean, Wlv, blv, out);
}

// Round 7
// 607.782 us; speedup vs baseline: 2.1586x; 1.0024x over previous
//
#include <hip/hip_runtime.h>

// Problem constants (fixed by the reference)
constexpr int N_  = 100000;
constexpr int E_  = 3200000;
constexpr int FIN = 16;
constexpr int H_  = 128;
constexpr int LAT = 64;
constexpr int L_  = 3;
constexpr int G_  = 1024;

// CSR bucketing: buckets of 512 nodes
constexpr int BSH = 9;
constexpr int BNODES = 1 << BSH;                    // 512
constexpr int NB_ = (N_ + BNODES - 1) / BNODES;     // 196
constexpr int FILL_NB = 512;
constexpr int FILL_CHUNK = E_ / FILL_NB;            // 6250 (exact)

using bf16x8 = __attribute__((ext_vector_type(8))) short;
using f32x4  = __attribute__((ext_vector_type(4))) float;

__device__ inline float bflo(unsigned int u) {   // low bf16 -> f32
  union { unsigned int i; float f; } v; v.i = u << 16; return v.f;
}
__device__ inline float bfhi(unsigned int u) {   // high bf16 -> f32
  union { unsigned int i; float f; } v; v.i = u & 0xffff0000u; return v.f;
}
__device__ inline unsigned short f2bf(float f) {
  union { float f; unsigned int i; } v; v.f = f;
  unsigned int r = v.i + 0x7fffu + ((v.i >> 16) & 1u);   // RNE
  return (unsigned short)(r >> 16);
}

// ---------------------------------------------------------------------------
// One-time: Wt[l][c][k] = bf16(Wmsg[l][k][c])   (transposed for B-fragments)
// ---------------------------------------------------------------------------
__global__ __launch_bounds__(256) void k_wconv(const float* __restrict__ W,
                                               unsigned short* __restrict__ Wt) {
  const int idx = blockIdx.x * 256 + threadIdx.x;      // over 3*128*128
  if (idx < L_ * H_ * H_) {
    const int l = idx >> 14, rem = idx & 16383;
    const int c = rem >> 7, k = rem & 127;
    Wt[idx] = f2bf(W[l * H_ * H_ + k * H_ + c]);
  }
}

// ---------------------------------------------------------------------------
// h = relu(x @ W_in + b_in) -> bf16.  4 nodes/block, lane owns 2 channels.
// ---------------------------------------------------------------------------
__global__ __launch_bounds__(256) void k_input(const float* __restrict__ x,
                                               const float* __restrict__ Win,
                                               const float* __restrict__ bin,
                                               unsigned short* __restrict__ h) {
  __shared__ float Wl[FIN * H_];   // 8 KB
  __shared__ float xl[4 * FIN];
  const int tid = threadIdx.x;
  for (int i = tid; i < FIN * H_; i += 256) Wl[i] = Win[i];
  const int n0 = blockIdx.x * 4;   // N divisible by 4
  if (tid < 4 * FIN) xl[tid] = x[(size_t)n0 * FIN + tid];
  __syncthreads();
  const int nl = tid >> 6, l = tid & 63;
  float a0 = bin[2 * l], a1 = bin[2 * l + 1];
#pragma unroll
  for (int k = 0; k < FIN; ++k) {
    const float xv = xl[nl * FIN + k];
    a0 += xv * Wl[k * H_ + 2 * l];
    a1 += xv * Wl[k * H_ + 2 * l + 1];
  }
  const unsigned int packed =
      (unsigned int)f2bf(fmaxf(a0, 0.f)) | ((unsigned int)f2bf(fmaxf(a1, 0.f)) << 16);
  *reinterpret_cast<unsigned int*>(h + (size_t)(n0 + nl) * H_ + 2 * l) = packed;
}

// ---------------------------------------------------------------------------
// m = h @ W + b  via MFMA (bf16 in, fp32 acc, bf16 out).  [N][H] layout.
// Block = 4 waves, tile 32 nodes x 128 cols; wave owns a 32x32 sub-tile.
// Epilogue: stage wave tile in padded LDS -> coalesced 16 B/lane stores.
// ---------------------------------------------------------------------------
__global__ __launch_bounds__(256) void k_msg_mfma(const unsigned short* __restrict__ h,
                                                  const unsigned short* __restrict__ Wt,
                                                  const float* __restrict__ b,
                                                  unsigned short* __restrict__ m) {
  __shared__ unsigned short st[4][32][40];   // 80 B row stride (16B-aligned), 10 KB
  const int wave = threadIdx.x >> 6;
  const int lane = threadIdx.x & 63;
  const int r = lane & 15;
  const int g = lane >> 4;               // 0..3
  const int n0 = blockIdx.x * 32;
  const int cb = wave * 32;

  f32x4 acc[2][2] = {};
#pragma unroll
  for (int kk = 0; kk < 4; ++kk) {
    const int koff = kk * 32 + g * 8;
    const bf16x8 a0 = *reinterpret_cast<const bf16x8*>(h + (size_t)(n0 + r) * H_ + koff);
    const bf16x8 a1 = *reinterpret_cast<const bf16x8*>(h + (size_t)(n0 + 16 + r) * H_ + koff);
    const bf16x8 b0 = *reinterpret_cast<const bf16x8*>(Wt + (size_t)(cb + r) * H_ + koff);
    const bf16x8 b1 = *reinterpret_cast<const bf16x8*>(Wt + (size_t)(cb + 16 + r) * H_ + koff);
    acc[0][0] = __builtin_amdgcn_mfma_f32_16x16x32_bf16(a0, b0, acc[0][0], 0, 0, 0);
    acc[0][1] = __builtin_amdgcn_mfma_f32_16x16x32_bf16(a0, b1, acc[0][1], 0, 0, 0);
    acc[1][0] = __builtin_amdgcn_mfma_f32_16x16x32_bf16(a1, b0, acc[1][0], 0, 0, 0);
    acc[1][1] = __builtin_amdgcn_mfma_f32_16x16x32_bf16(a1, b1, acc[1][1], 0, 0, 0);
  }

  const float bc0 = b[cb + r];
  const float bc1 = b[cb + 16 + r];
#pragma unroll
  for (int rt = 0; rt < 2; ++rt)
#pragma unroll
    for (int ct = 0; ct < 2; ++ct) {
      const float bc = ct ? bc1 : bc0;
#pragma unroll
      for (int j = 0; j < 4; ++j)
        st[wave][rt * 16 + g * 4 + j][ct * 16 + r] = f2bf(acc[rt][ct][j] + bc);
    }
  __syncthreads();
  // readback: 2 passes, 4 lanes/row, 16 B each -> 64 B contiguous per row
#pragma unroll
  for (int p = 0; p < 2; ++p) {
    const int lr = p * 16 + (lane >> 2);
    const int seg = lane & 3;
    const bf16x8 v = *reinterpret_cast<const bf16x8*>(&st[wave][lr][seg * 8]);
    *reinterpret_cast<bf16x8*>(m + (size_t)(n0 + lr) * H_ + cb + seg * 8) = v;
  }
}

// ---------------------------------------------------------------------------
// Bucketed CSR build (line-friendly counting sort, 4 small kernels)
// ebuf entry packed: (src << 9) | dst_local   (17 + 9 = 26 bits)
// ---------------------------------------------------------------------------
__global__ __launch_bounds__(256) void k_bhist(const int* __restrict__ ei,
                                               int* __restrict__ bcnt) {
  __shared__ int lh[NB_];
  for (int i = threadIdx.x; i < NB_; i += 256) lh[i] = 0;
  __syncthreads();
  const int gid = blockIdx.x * 256 + threadIdx.x;
  const int stride = gridDim.x * 256;
  for (int e = gid; e < E_; e += stride) atomicAdd(&lh[ei[E_ + e] >> BSH], 1);
  __syncthreads();
  for (int i = threadIdx.x; i < NB_; i += 256)
    if (lh[i]) atomicAdd(&bcnt[i], lh[i]);
}

__global__ __launch_bounds__(256) void k_bscan(const int* __restrict__ bcnt,
                                               int* __restrict__ boff,
                                               int* __restrict__ bcur) {
  __shared__ int s[256];
  const int t = threadIdx.x;
  s[t] = (t < NB_) ? bcnt[t] : 0;
  __syncthreads();
  for (int off = 1; off < 256; off <<= 1) {
    const int add = (t >= off) ? s[t - off] : 0;
    __syncthreads();
    s[t] += add;
    __syncthreads();
  }
  const int ex = (t == 0) ? 0 : s[t - 1];
  if (t < NB_) { boff[t] = ex; bcur[t] = ex; }
  if (t == 0) boff[NB_] = s[NB_ - 1];   // == E
}

__global__ __launch_bounds__(256) void k_bfill(const int* __restrict__ ei,
                                               int* __restrict__ bcur,
                                               unsigned int* __restrict__ ebuf) {
  __shared__ int lh[NB_], lbase[NB_];
  const int t = threadIdx.x;
  for (int i = t; i < NB_; i += 256) lh[i] = 0;
  __syncthreads();
  const int e0 = blockIdx.x * FILL_CHUNK;
  const int e1 = e0 + FILL_CHUNK;
  for (int e = e0 + t; e < e1; e += 256) atomicAdd(&lh[ei[E_ + e] >> BSH], 1);
  __syncthreads();
  for (int i = t; i < NB_; i += 256) {
    const int c = lh[i];
    lbase[i] = c ? atomicAdd(&bcur[i], c) : 0;
  }
  __syncthreads();
  for (int i = t; i < NB_; i += 256) lh[i] = 0;   // reuse as local cursor
  __syncthreads();
  for (int e = e0 + t; e < e1; e += 256) {
    const int src = ei[e], dst = ei[E_ + e];
    const int b = dst >> BSH;
    const int pos = lbase[b] + atomicAdd(&lh[b], 1);
    ebuf[pos] = ((unsigned)src << BSH) | (unsigned)(dst & (BNODES - 1));
  }
}

__global__ __launch_bounds__(256) void k_bcsr(const unsigned int* __restrict__ ebuf,
                                              const int* __restrict__ boff,
                                              int* __restrict__ rowp,
                                              int* __restrict__ ssrc) {
  __shared__ int sdeg[BNODES];
  __shared__ int scur[BNODES];
  __shared__ int part[256];
  const int b = blockIdx.x;
  const int nbase = b << BSH;
  const int ncnt = min(BNODES, N_ - nbase);
  const int ebeg = boff[b], eend = boff[b + 1];
  const int t = threadIdx.x;
  for (int i = t; i < BNODES; i += 256) { sdeg[i] = 0; scur[i] = 0; }
  __syncthreads();
  for (int e = ebeg + t; e < eend; e += 256)
    atomicAdd(&sdeg[ebuf[e] & (BNODES - 1)], 1);
  __syncthreads();
  // exclusive scan of sdeg[0..512) with 256 threads (2 elems each)
  const int i0 = 2 * t, i1 = 2 * t + 1;
  const int d0 = sdeg[i0];
  part[t] = d0 + sdeg[i1];
  __syncthreads();
  for (int off = 1; off < 256; off <<= 1) {
    const int add = (t >= off) ? part[t - off] : 0;
    __syncthreads();
    part[t] += add;
    __syncthreads();
  }
  const int ex = (t == 0) ? 0 : part[t - 1];
  sdeg[i0] = ex;
  sdeg[i1] = ex + d0;
  __syncthreads();
  for (int i = t; i < ncnt; i += 256) rowp[nbase + i] = ebeg + sdeg[i];
  if (b == NB_ - 1 && t == 0) rowp[N_] = E_;
  for (int e = ebeg + t; e < eend; e += 256) {
    const unsigned int ed = ebuf[e];
    const int ld = ed & (BNODES - 1);
    const int pos = ebeg + sdeg[ld] + atomicAdd(&scur[ld], 1);
    ssrc[pos] = (int)(ed >> BSH);
  }
}

// ---------------------------------------------------------------------------
// h[n] = relu( sum_{e in CSR[n]} m[ssrc[e]] )  bf16 rows, fp32 accum.
// 64 lanes per node (2 channels each), 4 nodes per 256-thread block.
// UNROLL 8: 8 outstanding 256 B row-loads per wave (latency hiding).
// NT loads for ssrc (streamed), NT stores for h (consumed next kernel).
// ---------------------------------------------------------------------------
__global__ __launch_bounds__(256) void k_gather(const unsigned short* __restrict__ m,
                                                const int* __restrict__ rowptr,
                                                const int* __restrict__ ssrc,
                                                unsigned short* __restrict__ h) {
  const int n = blockIdx.x * 4 + (threadIdx.x >> 6);
  const int c2 = threadIdx.x & 63;          // channel pair -> channels 2c2, 2c2+1
  const int beg = rowptr[n], end = rowptr[n + 1];
  const unsigned short* mc = m + 2 * c2;
  float a0 = 0.f, a1 = 0.f;
  int i = beg;
  for (; i + 7 < end; i += 8) {
    int s[8];
#pragma unroll
    for (int u = 0; u < 8; ++u) s[u] = __builtin_nontemporal_load(ssrc + i + u);
    unsigned int v[8];
#pragma unroll
    for (int u = 0; u < 8; ++u)
      v[u] = *reinterpret_cast<const unsigned int*>(mc + (size_t)s[u] * H_);
#pragma unroll
    for (int u = 0; u < 8; ++u) { a0 += bflo(v[u]); a1 += bfhi(v[u]); }
  }
  for (; i + 1 < end; i += 2) {
    const int s0 = ssrc[i];
    const int s1 = ssrc[i + 1];
    const unsigned int v0 = *reinterpret_cast<const unsigned int*>(mc + (size_t)s0 * H_);
    const unsigned int v1 = *reinterpret_cast<const unsigned int*>(mc + (size_t)s1 * H_);
    a0 += bflo(v0);  a1 += bfhi(v0);
    a0 += bflo(v1);  a1 += bfhi(v1);
  }
  if (i < end) {
    const unsigned int v = *reinterpret_cast<const unsigned int*>(mc + (size_t)ssrc[i] * H_);
    a0 += bflo(v);  a1 += bfhi(v);
  }
  const unsigned int packed =
      (unsigned int)f2bf(fmaxf(a0, 0.f)) | ((unsigned int)f2bf(fmaxf(a1, 0.f)) << 16);
  __builtin_nontemporal_store(packed,
      reinterpret_cast<unsigned int*>(h + (size_t)n * H_ + 2 * c2));
}

// ---------------------------------------------------------------------------
// ge[g] += h[n] (h already post-relu) with batch sorted: running sum + flush.
// ---------------------------------------------------------------------------
constexpr int POOL_CHUNK = 128;
__global__ __launch_bounds__(128) void k_pool(const unsigned short* __restrict__ h,
                                              const int* __restrict__ batch,
                                              float* __restrict__ ge) {
  __shared__ int bl[POOL_CHUNK];
  const int tid = threadIdx.x;
  const int start = blockIdx.x * POOL_CHUNK;
  const int cnt = min(POOL_CHUNK, N_ - start);
  if (tid < cnt) bl[tid] = batch[start + tid];
  __syncthreads();
  float run = 0.f;
  int cur = bl[0];
  for (int i = 0; i < cnt; ++i) {
    const int bid = bl[i];
    const float v = bflo((unsigned int)h[(size_t)(start + i) * H_ + tid]);
    if (bid != cur) {
      unsafeAtomicAdd(&ge[(size_t)cur * H_ + tid], run);
      run = 0.f;
      cur = bid;
    }
    run += v;
  }
  unsafeAtomicAdd(&ge[(size_t)cur * H_ + tid], run);
}

// ---------------------------------------------------------------------------
// out = [ge @ W_mean + b_mean ; ge @ W_logvar + b_logvar]
// ---------------------------------------------------------------------------
__global__ __launch_bounds__(128) void k_out(const float* __restrict__ ge,
                                             const float* __restrict__ Wm,
                                             const float* __restrict__ bm,
                                             const float* __restrict__ Wv,
                                             const float* __restrict__ bv,
                                             float* __restrict__ out) {
  __shared__ float gl[H_];
  const int g = blockIdx.x, tid = threadIdx.x;
  gl[tid] = ge[(size_t)g * H_ + tid];
  __syncthreads();
  const bool is_mean = (tid < LAT);
  const float* W = is_mean ? Wm : Wv;
  const float* bb = is_mean ? bm : bv;
  const int c = tid & 63;
  float acc = bb[c];
#pragma unroll 8
  for (int k = 0; k < H_; ++k) acc += gl[k] * W[k * LAT + c];
  const size_t off = is_mean ? 0 : (size_t)G_ * LAT;
  out[off + (size_t)g * LAT + c] = acc;
}

// ---------------------------------------------------------------------------
extern "C" void kernel_launch(void* const* d_in, const int* in_sizes, int n_in,
                              void* d_out, int out_size, void* d_ws, size_t ws_size,
                              hipStream_t stream) {
  const float* x     = (const float*)d_in[0];
  const int*   ei    = (const int*)d_in[1];   // [2,E] int32
  const int*   batch = (const int*)d_in[2];   // [N]  int32 (sorted)
  const float* Win   = (const float*)d_in[4];
  const float* bin   = (const float*)d_in[5];
  const float* Wmsg  = (const float*)d_in[6];
  const float* bmsg  = (const float*)d_in[7];
  const float* Wmean = (const float*)d_in[8];
  const float* bmean = (const float*)d_in[9];
  const float* Wlv   = (const float*)d_in[10];
  const float* blv   = (const float*)d_in[11];
  float* out = (float*)d_out;

  // workspace layout (bytes), large-first for alignment
  char* p = (char*)d_ws;
  unsigned short* h  = (unsigned short*)p;  p += (size_t)N_ * H_ * 2;   // 25.6 MB
  unsigned short* m  = (unsigned short*)p;  p += (size_t)N_ * H_ * 2;   // 25.6 MB
  unsigned int* ebuf = (unsigned int*)p;    p += (size_t)E_ * 4;        // 12.8 MB
  int* ssrc          = (int*)p;             p += (size_t)E_ * 4;        // 12.8 MB
  int* rowp          = (int*)p;             p += (size_t)(N_ + 1) * 4;
  unsigned short* Wt = (unsigned short*)p;  p += (size_t)L_ * H_ * H_ * 2;
  float* ge          = (float*)p;           p += (size_t)G_ * H_ * 4;
  int* bcnt          = (int*)p;             p += (size_t)NB_ * 4;
  int* boff          = (int*)p;             p += (size_t)(NB_ + 1) * 4;
  int* bcur          = (int*)p;             p += (size_t)NB_ * 4;

  // ---- one-time weight convert+transpose ----
  k_wconv<<<(L_ * H_ * H_ + 255) / 256, 256, 0, stream>>>(Wmsg, Wt);

  // ---- bucketed CSR build (once; edge list shared by all 3 layers) ----
  hipMemsetAsync(bcnt, 0, (size_t)NB_ * sizeof(int), stream);
  k_bhist<<<256, 256, 0, stream>>>(ei, bcnt);
  k_bscan<<<1, 256, 0, stream>>>(bcnt, boff, bcur);
  k_bfill<<<FILL_NB, 256, 0, stream>>>(ei, bcur, ebuf);
  k_bcsr<<<NB_, 256, 0, stream>>>(ebuf, boff, rowp, ssrc);

  // ---- h = relu(x @ W_in + b_in) ----
  k_input<<<N_ / 4, 256, 0, stream>>>(x, Win, bin, h);

  for (int l = 0; l < L_; ++l) {
    k_msg_mfma<<<N_ / 32, 256, 0, stream>>>(h, Wt + (size_t)l * H_ * H_,
                                            bmsg + (size_t)l * H_, m);
    k_gather<<<N_ / 4, 256, 0, stream>>>(m, rowp, ssrc, h);
  }

  // ---- graph pooling ----
  hipMemsetAsync(ge, 0, (size_t)G_ * H_ * sizeof(float), stream);
  k_pool<<<(N_ + POOL_CHUNK - 1) / POOL_CHUNK, 128, 0, stream>>>(h, batch, ge);

  // ---- heads ----
  k_out<<<G_, 128, 0, stream>>>(ge, Wmean, bmean, Wlv, blv, out);
}

// Round 8
// 559.341 us; speedup vs baseline: 2.3456x; 1.0866x over previous
//
#include <hip/hip_runtime.h>

// Problem constants (fixed by the reference)
constexpr int N_  = 100000;
constexpr int E_  = 3200000;
constexpr int FIN = 16;
constexpr int H_  = 128;
constexpr int LAT = 64;
constexpr int L_  = 3;
constexpr int G_  = 1024;

// CSR bucketing: buckets of 512 nodes
constexpr int BSH = 9;
constexpr int BNODES = 1 << BSH;                    // 512
constexpr int NB_ = (N_ + BNODES - 1) / BNODES;     // 196
constexpr int FILL_NB = 512;
constexpr int FILL_CHUNK = E_ / FILL_NB;            // 6250 (exact)

using bf16x8 = __attribute__((ext_vector_type(8))) short;
using f32x4  = __attribute__((ext_vector_type(4))) float;

__device__ inline float bflo(unsigned int u) {   // low bf16 -> f32
  union { unsigned int i; float f; } v; v.i = u << 16; return v.f;
}
__device__ inline float bfhi(unsigned int u) {   // high bf16 -> f32
  union { unsigned int i; float f; } v; v.i = u & 0xffff0000u; return v.f;
}
__device__ inline unsigned short f2bf(float f) {
  union { float f; unsigned int i; } v; v.f = f;
  unsigned int r = v.i + 0x7fffu + ((v.i >> 16) & 1u);   // RNE
  return (unsigned short)(r >> 16);
}

// ---------------------------------------------------------------------------
// One-time: Wt[l][c][k] = bf16(Wmsg[l][k][c]); block 0 also zeroes bcnt
// (folds the bcnt memset; bcnt consumed only by k_bhist, later in stream).
// ---------------------------------------------------------------------------
__global__ __launch_bounds__(256) void k_wconv(const float* __restrict__ W,
                                               unsigned short* __restrict__ Wt,
                                               int* __restrict__ bcnt) {
  if (blockIdx.x == 0) {
    for (int i = threadIdx.x; i < NB_; i += 256) bcnt[i] = 0;
  }
  const int idx = blockIdx.x * 256 + threadIdx.x;      // over 3*128*128
  if (idx < L_ * H_ * H_) {
    const int l = idx >> 14, rem = idx & 16383;
    const int c = rem >> 7, k = rem & 127;
    Wt[idx] = f2bf(W[l * H_ * H_ + k * H_ + c]);
  }
}

// ---------------------------------------------------------------------------
// h = relu(x @ W_in + b_in) -> bf16.  4 nodes/block, lane owns 2 channels.
// ---------------------------------------------------------------------------
__global__ __launch_bounds__(256) void k_input(const float* __restrict__ x,
                                               const float* __restrict__ Win,
                                               const float* __restrict__ bin,
                                               unsigned short* __restrict__ h) {
  __shared__ float Wl[FIN * H_];   // 8 KB
  __shared__ float xl[4 * FIN];
  const int tid = threadIdx.x;
  for (int i = tid; i < FIN * H_; i += 256) Wl[i] = Win[i];
  const int n0 = blockIdx.x * 4;   // N divisible by 4
  if (tid < 4 * FIN) xl[tid] = x[(size_t)n0 * FIN + tid];
  __syncthreads();
  const int nl = tid >> 6, l = tid & 63;
  float a0 = bin[2 * l], a1 = bin[2 * l + 1];
#pragma unroll
  for (int k = 0; k < FIN; ++k) {
    const float xv = xl[nl * FIN + k];
    a0 += xv * Wl[k * H_ + 2 * l];
    a1 += xv * Wl[k * H_ + 2 * l + 1];
  }
  const unsigned int packed =
      (unsigned int)f2bf(fmaxf(a0, 0.f)) | ((unsigned int)f2bf(fmaxf(a1, 0.f)) << 16);
  *reinterpret_cast<unsigned int*>(h + (size_t)(n0 + nl) * H_ + 2 * l) = packed;
}

// ---------------------------------------------------------------------------
// m = h @ W + b  via MFMA (bf16 in, fp32 acc, bf16 out).  [N][H] layout.
// Block = 4 waves, tile 32 nodes x 128 cols; wave owns a 32x32 sub-tile.
// Epilogue: stage wave tile in padded LDS -> coalesced 16 B/lane stores.
// ---------------------------------------------------------------------------
__global__ __launch_bounds__(256) void k_msg_mfma(const unsigned short* __restrict__ h,
                                                  const unsigned short* __restrict__ Wt,
                                                  const float* __restrict__ b,
                                                  unsigned short* __restrict__ m) {
  __shared__ unsigned short st[4][32][40];   // 80 B row stride (16B-aligned), 10 KB
  const int wave = threadIdx.x >> 6;
  const int lane = threadIdx.x & 63;
  const int r = lane & 15;
  const int g = lane >> 4;               // 0..3
  const int n0 = blockIdx.x * 32;
  const int cb = wave * 32;

  f32x4 acc[2][2] = {};
#pragma unroll
  for (int kk = 0; kk < 4; ++kk) {
    const int koff = kk * 32 + g * 8;
    const bf16x8 a0 = *reinterpret_cast<const bf16x8*>(h + (size_t)(n0 + r) * H_ + koff);
    const bf16x8 a1 = *reinterpret_cast<const bf16x8*>(h + (size_t)(n0 + 16 + r) * H_ + koff);
    const bf16x8 b0 = *reinterpret_cast<const bf16x8*>(Wt + (size_t)(cb + r) * H_ + koff);
    const bf16x8 b1 = *reinterpret_cast<const bf16x8*>(Wt + (size_t)(cb + 16 + r) * H_ + koff);
    acc[0][0] = __builtin_amdgcn_mfma_f32_16x16x32_bf16(a0, b0, acc[0][0], 0, 0, 0);
    acc[0][1] = __builtin_amdgcn_mfma_f32_16x16x32_bf16(a0, b1, acc[0][1], 0, 0, 0);
    acc[1][0] = __builtin_amdgcn_mfma_f32_16x16x32_bf16(a1, b0, acc[1][0], 0, 0, 0);
    acc[1][1] = __builtin_amdgcn_mfma_f32_16x16x32_bf16(a1, b1, acc[1][1], 0, 0, 0);
  }

  const float bc0 = b[cb + r];
  const float bc1 = b[cb + 16 + r];
#pragma unroll
  for (int rt = 0; rt < 2; ++rt)
#pragma unroll
    for (int ct = 0; ct < 2; ++ct) {
      const float bc = ct ? bc1 : bc0;
#pragma unroll
      for (int j = 0; j < 4; ++j)
        st[wave][rt * 16 + g * 4 + j][ct * 16 + r] = f2bf(acc[rt][ct][j] + bc);
    }
  __syncthreads();
  // readback: 2 passes, 4 lanes/row, 16 B each -> 64 B contiguous per row
#pragma unroll
  for (int p = 0; p < 2; ++p) {
    const int lr = p * 16 + (lane >> 2);
    const int seg = lane & 3;
    const bf16x8 v = *reinterpret_cast<const bf16x8*>(&st[wave][lr][seg * 8]);
    *reinterpret_cast<bf16x8*>(m + (size_t)(n0 + lr) * H_ + cb + seg * 8) = v;
  }
}

// ---------------------------------------------------------------------------
// Bucketed CSR build (line-friendly counting sort, 4 small kernels)
// ebuf entry packed: (src << 9) | dst_local   (17 + 9 = 26 bits)
// ---------------------------------------------------------------------------
__global__ __launch_bounds__(256) void k_bhist(const int* __restrict__ ei,
                                               int* __restrict__ bcnt) {
  __shared__ int lh[NB_];
  for (int i = threadIdx.x; i < NB_; i += 256) lh[i] = 0;
  __syncthreads();
  const int gid = blockIdx.x * 256 + threadIdx.x;
  const int stride = gridDim.x * 256;
  for (int e = gid; e < E_; e += stride) atomicAdd(&lh[ei[E_ + e] >> BSH], 1);
  __syncthreads();
  for (int i = threadIdx.x; i < NB_; i += 256)
    if (lh[i]) atomicAdd(&bcnt[i], lh[i]);
}

// scan buckets -> boff/bcur; also zeroes ge (folds the ge memset; ge consumed
// by k_pool much later in stream order).
__global__ __launch_bounds__(256) void k_bscan(const int* __restrict__ bcnt,
                                               int* __restrict__ boff,
                                               int* __restrict__ bcur,
                                               float* __restrict__ ge) {
  __shared__ int s[256];
  const int t = threadIdx.x;
  s[t] = (t < NB_) ? bcnt[t] : 0;
  __syncthreads();
  for (int off = 1; off < 256; off <<= 1) {
    const int add = (t >= off) ? s[t - off] : 0;
    __syncthreads();
    s[t] += add;
    __syncthreads();
  }
  const int ex = (t == 0) ? 0 : s[t - 1];
  if (t < NB_) { boff[t] = ex; bcur[t] = ex; }
  if (t == 0) boff[NB_] = s[NB_ - 1];   // == E
  float4 z = make_float4(0.f, 0.f, 0.f, 0.f);
  float4* g4 = reinterpret_cast<float4*>(ge);
  for (int i = t; i < G_ * H_ / 4; i += 256) g4[i] = z;
}

__global__ __launch_bounds__(256) void k_bfill(const int* __restrict__ ei,
                                               int* __restrict__ bcur,
                                               unsigned int* __restrict__ ebuf) {
  __shared__ int lh[NB_], lbase[NB_];
  const int t = threadIdx.x;
  for (int i = t; i < NB_; i += 256) lh[i] = 0;
  __syncthreads();
  const int e0 = blockIdx.x * FILL_CHUNK;
  const int e1 = e0 + FILL_CHUNK;
  for (int e = e0 + t; e < e1; e += 256) atomicAdd(&lh[ei[E_ + e] >> BSH], 1);
  __syncthreads();
  for (int i = t; i < NB_; i += 256) {
    const int c = lh[i];
    lbase[i] = c ? atomicAdd(&bcur[i], c) : 0;
  }
  __syncthreads();
  for (int i = t; i < NB_; i += 256) lh[i] = 0;   // reuse as local cursor
  __syncthreads();
  for (int e = e0 + t; e < e1; e += 256) {
    const int src = ei[e], dst = ei[E_ + e];
    const int b = dst >> BSH;
    const int pos = lbase[b] + atomicAdd(&lh[b], 1);
    ebuf[pos] = ((unsigned)src << BSH) | (unsigned)(dst & (BNODES - 1));
  }
}

__global__ __launch_bounds__(256) void k_bcsr(const unsigned int* __restrict__ ebuf,
                                              const int* __restrict__ boff,
                                              int* __restrict__ rowp,
                                              int* __restrict__ ssrc) {
  __shared__ int sdeg[BNODES];
  __shared__ int scur[BNODES];
  __shared__ int part[256];
  const int b = blockIdx.x;
  const int nbase = b << BSH;
  const int ncnt = min(BNODES, N_ - nbase);
  const int ebeg = boff[b], eend = boff[b + 1];
  const int t = threadIdx.x;
  for (int i = t; i < BNODES; i += 256) { sdeg[i] = 0; scur[i] = 0; }
  __syncthreads();
  for (int e = ebeg + t; e < eend; e += 256)
    atomicAdd(&sdeg[ebuf[e] & (BNODES - 1)], 1);
  __syncthreads();
  // exclusive scan of sdeg[0..512) with 256 threads (2 elems each)
  const int i0 = 2 * t, i1 = 2 * t + 1;
  const int d0 = sdeg[i0];
  part[t] = d0 + sdeg[i1];
  __syncthreads();
  for (int off = 1; off < 256; off <<= 1) {
    const int add = (t >= off) ? part[t - off] : 0;
    __syncthreads();
    part[t] += add;
    __syncthreads();
  }
  const int ex = (t == 0) ? 0 : part[t - 1];
  sdeg[i0] = ex;
  sdeg[i1] = ex + d0;
  __syncthreads();
  for (int i = t; i < ncnt; i += 256) rowp[nbase + i] = ebeg + sdeg[i];
  if (b == NB_ - 1 && t == 0) rowp[N_] = E_;
  for (int e = ebeg + t; e < eend; e += 256) {
    const unsigned int ed = ebuf[e];
    const int ld = ed & (BNODES - 1);
    const int pos = ebeg + sdeg[ld] + atomicAdd(&scur[ld], 1);
    ssrc[pos] = (int)(ed >> BSH);
  }
}

// ---------------------------------------------------------------------------
// h[n] = relu( sum_{e in CSR[n]} m[ssrc[e]] )  bf16 rows, fp32 accum.
// 64 lanes per node (2 channels each), 4 nodes per 256-thread block.
// UNROLL 16: up to 16 outstanding 256 B row-loads per wave.
// ---------------------------------------------------------------------------
__global__ __launch_bounds__(256) void k_gather(const unsigned short* __restrict__ m,
                                                const int* __restrict__ rowptr,
                                                const int* __restrict__ ssrc,
                                                unsigned short* __restrict__ h) {
  const int n = blockIdx.x * 4 + (threadIdx.x >> 6);
  const int c2 = threadIdx.x & 63;          // channel pair -> channels 2c2, 2c2+1
  const int beg = rowptr[n], end = rowptr[n + 1];
  const unsigned short* mc = m + 2 * c2;
  float a0 = 0.f, a1 = 0.f;
  int i = beg;
  for (; i + 15 < end; i += 16) {
    int s[16];
#pragma unroll
    for (int u = 0; u < 16; ++u) s[u] = ssrc[i + u];
    unsigned int v[16];
#pragma unroll
    for (int u = 0; u < 16; ++u)
      v[u] = *reinterpret_cast<const unsigned int*>(mc + (size_t)s[u] * H_);
#pragma unroll
    for (int u = 0; u < 16; ++u) { a0 += bflo(v[u]); a1 += bfhi(v[u]); }
  }
  for (; i + 3 < end; i += 4) {
    int s[4];
#pragma unroll
    for (int u = 0; u < 4; ++u) s[u] = ssrc[i + u];
    unsigned int v[4];
#pragma unroll
    for (int u = 0; u < 4; ++u)
      v[u] = *reinterpret_cast<const unsigned int*>(mc + (size_t)s[u] * H_);
#pragma unroll
    for (int u = 0; u < 4; ++u) { a0 += bflo(v[u]); a1 += bfhi(v[u]); }
  }
  for (; i < end; ++i) {
    const unsigned int v = *reinterpret_cast<const unsigned int*>(mc + (size_t)ssrc[i] * H_);
    a0 += bflo(v);  a1 += bfhi(v);
  }
  const unsigned int packed =
      (unsigned int)f2bf(fmaxf(a0, 0.f)) | ((unsigned int)f2bf(fmaxf(a1, 0.f)) << 16);
  *reinterpret_cast<unsigned int*>(h + (size_t)n * H_ + 2 * c2) = packed;
}

// ---------------------------------------------------------------------------
// ge[g] += h[n] (h already post-relu) with batch sorted: running sum + flush.
// ---------------------------------------------------------------------------
constexpr int POOL_CHUNK = 128;
__global__ __launch_bounds__(128) void k_pool(const unsigned short* __restrict__ h,
                                              const int* __restrict__ batch,
                                              float* __restrict__ ge) {
  __shared__ int bl[POOL_CHUNK];
  const int tid = threadIdx.x;
  const int start = blockIdx.x * POOL_CHUNK;
  const int cnt = min(POOL_CHUNK, N_ - start);
  if (tid < cnt) bl[tid] = batch[start + tid];
  __syncthreads();
  float run = 0.f;
  int cur = bl[0];
  for (int i = 0; i < cnt; ++i) {
    const int bid = bl[i];
    const float v = bflo((unsigned int)h[(size_t)(start + i) * H_ + tid]);
    if (bid != cur) {
      unsafeAtomicAdd(&ge[(size_t)cur * H_ + tid], run);
      run = 0.f;
      cur = bid;
    }
    run += v;
  }
  unsafeAtomicAdd(&ge[(size_t)cur * H_ + tid], run);
}

// ---------------------------------------------------------------------------
// out = [ge @ W_mean + b_mean ; ge @ W_logvar + b_logvar]
// ---------------------------------------------------------------------------
__global__ __launch_bounds__(128) void k_out(const float* __restrict__ ge,
                                             const float* __restrict__ Wm,
                                             const float* __restrict__ bm,
                                             const float* __restrict__ Wv,
                                             const float* __restrict__ bv,
                                             float* __restrict__ out) {
  __shared__ float gl[H_];
  const int g = blockIdx.x, tid = threadIdx.x;
  gl[tid] = ge[(size_t)g * H_ + tid];
  __syncthreads();
  const bool is_mean = (tid < LAT);
  const float* W = is_mean ? Wm : Wv;
  const float* bb = is_mean ? bm : bv;
  const int c = tid & 63;
  float acc = bb[c];
#pragma unroll 8
  for (int k = 0; k < H_; ++k) acc += gl[k] * W[k * LAT + c];
  const size_t off = is_mean ? 0 : (size_t)G_ * LAT;
  out[off + (size_t)g * LAT + c] = acc;
}

// ---------------------------------------------------------------------------
extern "C" void kernel_launch(void* const* d_in, const int* in_sizes, int n_in,
                              void* d_out, int out_size, void* d_ws, size_t ws_size,
                              hipStream_t stream) {
  const float* x     = (const float*)d_in[0];
  const int*   ei    = (const int*)d_in[1];   // [2,E] int32
  const int*   batch = (const int*)d_in[2];   // [N]  int32 (sorted)
  const float* Win   = (const float*)d_in[4];
  const float* bin   = (const float*)d_in[5];
  const float* Wmsg  = (const float*)d_in[6];
  const float* bmsg  = (const float*)d_in[7];
  const float* Wmean = (const float*)d_in[8];
  const float* bmean = (const float*)d_in[9];
  const float* Wlv   = (const float*)d_in[10];
  const float* blv   = (const float*)d_in[11];
  float* out = (float*)d_out;

  // workspace layout (bytes), large-first for alignment
  char* p = (char*)d_ws;
  unsigned short* h  = (unsigned short*)p;  p += (size_t)N_ * H_ * 2;   // 25.6 MB
  unsigned short* m  = (unsigned short*)p;  p += (size_t)N_ * H_ * 2;   // 25.6 MB
  unsigned int* ebuf = (unsigned int*)p;    p += (size_t)E_ * 4;        // 12.8 MB
  int* ssrc          = (int*)p;             p += (size_t)E_ * 4;        // 12.8 MB
  int* rowp          = (int*)p;             p += (size_t)(N_ + 1) * 4;
  unsigned short* Wt = (unsigned short*)p;  p += (size_t)L_ * H_ * H_ * 2;
  float* ge          = (float*)p;           p += (size_t)G_ * H_ * 4;
  int* bcnt          = (int*)p;             p += (size_t)NB_ * 4;
  int* boff          = (int*)p;             p += (size_t)(NB_ + 1) * 4;
  int* bcur          = (int*)p;             p += (size_t)NB_ * 4;

  // ---- one-time weight convert+transpose (+ bcnt zero) ----
  k_wconv<<<(L_ * H_ * H_ + 255) / 256, 256, 0, stream>>>(Wmsg, Wt, bcnt);

  // ---- bucketed CSR build (once; edge list shared by all 3 layers) ----
  k_bhist<<<256, 256, 0, stream>>>(ei, bcnt);
  k_bscan<<<1, 256, 0, stream>>>(bcnt, boff, bcur, ge);   // also zeroes ge
  k_bfill<<<FILL_NB, 256, 0, stream>>>(ei, bcur, ebuf);
  k_bcsr<<<NB_, 256, 0, stream>>>(ebuf, boff, rowp, ssrc);

  // ---- h = relu(x @ W_in + b_in) ----
  k_input<<<N_ / 4, 256, 0, stream>>>(x, Win, bin, h);

  for (int l = 0; l < L_; ++l) {
    k_msg_mfma<<<N_ / 32, 256, 0, stream>>>(h, Wt + (size_t)l * H_ * H_,
                                            bmsg + (size_t)l * H_, m);
    k_gather<<<N_ / 4, 256, 0, stream>>>(m, rowp, ssrc, h);
  }

  // ---- graph pooling ----
  k_pool<<<(N_ + POOL_CHUNK - 1) / POOL_CHUNK, 128, 0, stream>>>(h, batch, ge);

  // ---- heads ----
  k_out<<<G_, 128, 0, stream>>>(ge, Wmean, bmean, Wlv, blv, out);
}

// Round 9
// 558.987 us; speedup vs baseline: 2.3471x; 1.0006x over previous
//
#include <hip/hip_runtime.h>

// Problem constants (fixed by the reference)
constexpr int N_  = 100000;
constexpr int E_  = 3200000;
constexpr int FIN = 16;
constexpr int H_  = 128;
constexpr int LAT = 64;
constexpr int L_  = 3;
constexpr int G_  = 1024;

// CSR bucketing: buckets of 512 nodes
constexpr int BSH = 9;
constexpr int BNODES = 1 << BSH;                    // 512
constexpr int NB_ = (N_ + BNODES - 1) / BNODES;     // 196
constexpr int FILL_NB = 512;
constexpr int FILL_CHUNK = E_ / FILL_NB;            // 6250 (exact)

constexpr int WCONV_BLOCKS = (L_ * H_ * H_) / 256;  // 192

using bf16x8 = __attribute__((ext_vector_type(8))) short;
using f32x4  = __attribute__((ext_vector_type(4))) float;

__device__ inline float bflo(unsigned int u) {   // low bf16 -> f32
  union { unsigned int i; float f; } v; v.i = u << 16; return v.f;
}
__device__ inline float bfhi(unsigned int u) {   // high bf16 -> f32
  union { unsigned int i; float f; } v; v.i = u & 0xffff0000u; return v.f;
}
__device__ inline unsigned short f2bf(float f) {
  union { float f; unsigned int i; } v; v.f = f;
  unsigned int r = v.i + 0x7fffu + ((v.i >> 16) & 1u);   // RNE
  return (unsigned short)(r >> 16);
}

// ---------------------------------------------------------------------------
// Fused init: blocks [0,192): Wt[l][c][k] = bf16(W[l][k][c]) (+ bcnt zero);
// blocks [192,...): h = relu(x @ W_in + b_in) -> bf16, 4 nodes/block.
// ---------------------------------------------------------------------------
__global__ __launch_bounds__(256) void k_winit(const float* __restrict__ W,
                                               unsigned short* __restrict__ Wt,
                                               int* __restrict__ bcnt,
                                               const float* __restrict__ x,
                                               const float* __restrict__ Win,
                                               const float* __restrict__ bin,
                                               unsigned short* __restrict__ h) {
  const int tid = threadIdx.x;
  if (blockIdx.x < WCONV_BLOCKS) {
    if (blockIdx.x == 0)
      for (int i = tid; i < NB_; i += 256) bcnt[i] = 0;
    const int idx = blockIdx.x * 256 + tid;            // over 3*128*128
    const int l = idx >> 14, rem = idx & 16383;
    const int c = rem >> 7, k = rem & 127;
    Wt[idx] = f2bf(W[l * H_ * H_ + k * H_ + c]);
    return;
  }
  __shared__ float Wl[FIN * H_];   // 8 KB
  __shared__ float xl[4 * FIN];
  for (int i = tid; i < FIN * H_; i += 256) Wl[i] = Win[i];
  const int n0 = (blockIdx.x - WCONV_BLOCKS) * 4;      // N divisible by 4
  if (tid < 4 * FIN) xl[tid] = x[(size_t)n0 * FIN + tid];
  __syncthreads();
  const int nl = tid >> 6, l = tid & 63;
  float a0 = bin[2 * l], a1 = bin[2 * l + 1];
#pragma unroll
  for (int k = 0; k < FIN; ++k) {
    const float xv = xl[nl * FIN + k];
    a0 += xv * Wl[k * H_ + 2 * l];
    a1 += xv * Wl[k * H_ + 2 * l + 1];
  }
  const unsigned int packed =
      (unsigned int)f2bf(fmaxf(a0, 0.f)) | ((unsigned int)f2bf(fmaxf(a1, 0.f)) << 16);
  *reinterpret_cast<unsigned int*>(h + (size_t)(n0 + nl) * H_ + 2 * l) = packed;
}

// ---------------------------------------------------------------------------
// m = h @ W + b  via MFMA (bf16 in, fp32 acc, bf16 out).  [N][H] layout.
// Block = 4 waves, tile 32 nodes x 128 cols; wave owns a 32x32 sub-tile.
// Epilogue: stage wave tile in padded LDS -> coalesced 16 B/lane stores.
// ---------------------------------------------------------------------------
__global__ __launch_bounds__(256) void k_msg_mfma(const unsigned short* __restrict__ h,
                                                  const unsigned short* __restrict__ Wt,
                                                  const float* __restrict__ b,
                                                  unsigned short* __restrict__ m) {
  __shared__ unsigned short st[4][32][40];   // 80 B row stride, 10 KB
  const int wave = threadIdx.x >> 6;
  const int lane = threadIdx.x & 63;
  const int r = lane & 15;
  const int g = lane >> 4;               // 0..3
  const int n0 = blockIdx.x * 32;
  const int cb = wave * 32;

  f32x4 acc[2][2] = {};
#pragma unroll
  for (int kk = 0; kk < 4; ++kk) {
    const int koff = kk * 32 + g * 8;
    const bf16x8 a0 = *reinterpret_cast<const bf16x8*>(h + (size_t)(n0 + r) * H_ + koff);
    const bf16x8 a1 = *reinterpret_cast<const bf16x8*>(h + (size_t)(n0 + 16 + r) * H_ + koff);
    const bf16x8 b0 = *reinterpret_cast<const bf16x8*>(Wt + (size_t)(cb + r) * H_ + koff);
    const bf16x8 b1 = *reinterpret_cast<const bf16x8*>(Wt + (size_t)(cb + 16 + r) * H_ + koff);
    acc[0][0] = __builtin_amdgcn_mfma_f32_16x16x32_bf16(a0, b0, acc[0][0], 0, 0, 0);
    acc[0][1] = __builtin_amdgcn_mfma_f32_16x16x32_bf16(a0, b1, acc[0][1], 0, 0, 0);
    acc[1][0] = __builtin_amdgcn_mfma_f32_16x16x32_bf16(a1, b0, acc[1][0], 0, 0, 0);
    acc[1][1] = __builtin_amdgcn_mfma_f32_16x16x32_bf16(a1, b1, acc[1][1], 0, 0, 0);
  }

  const float bc0 = b[cb + r];
  const float bc1 = b[cb + 16 + r];
#pragma unroll
  for (int rt = 0; rt < 2; ++rt)
#pragma unroll
    for (int ct = 0; ct < 2; ++ct) {
      const float bc = ct ? bc1 : bc0;
#pragma unroll
      for (int j = 0; j < 4; ++j)
        st[wave][rt * 16 + g * 4 + j][ct * 16 + r] = f2bf(acc[rt][ct][j] + bc);
    }
  __syncthreads();
#pragma unroll
  for (int p = 0; p < 2; ++p) {
    const int lr = p * 16 + (lane >> 2);
    const int seg = lane & 3;
    const bf16x8 v = *reinterpret_cast<const bf16x8*>(&st[wave][lr][seg * 8]);
    *reinterpret_cast<bf16x8*>(m + (size_t)(n0 + lr) * H_ + cb + seg * 8) = v;
  }
}

// ---------------------------------------------------------------------------
// FUSED gather + msg:  h_tile = relu(gather(m_in)) kept in LDS (never global),
// then m_out tile = h_tile @ Wt + b via MFMA.
// Block = 32 nodes; gather: wave w handles nodes w*8..w*8+7, 64 lanes = 128 ch,
// unroll-16 row loads (same proven inner loop as k_gather).
// ---------------------------------------------------------------------------
__global__ __launch_bounds__(256) void k_gm(const unsigned short* __restrict__ m_in,
                                            const int* __restrict__ rowptr,
                                            const int* __restrict__ ssrc,
                                            const unsigned short* __restrict__ Wt,
                                            const float* __restrict__ b,
                                            unsigned short* __restrict__ m_out) {
  __shared__ unsigned int hl[32][68];        // h tile (uint = 2 bf16), +4 pad, 8.7 KB
  __shared__ unsigned short st[4][32][40];   // epilogue staging, 10 KB
  const int wave = threadIdx.x >> 6;
  const int lane = threadIdx.x & 63;
  const int n0 = blockIdx.x * 32;
  const unsigned short* mc = m_in + 2 * lane;

  // ---- gather phase ----
  for (int j = 0; j < 8; ++j) {
    const int row = wave * 8 + j;
    const int n = n0 + row;
    const int beg = rowptr[n], end = rowptr[n + 1];
    float a0 = 0.f, a1 = 0.f;
    int i = beg;
    for (; i + 15 < end; i += 16) {
      int s[16];
#pragma unroll
      for (int u = 0; u < 16; ++u) s[u] = ssrc[i + u];
      unsigned int v[16];
#pragma unroll
      for (int u = 0; u < 16; ++u)
        v[u] = *reinterpret_cast<const unsigned int*>(mc + (size_t)s[u] * H_);
#pragma unroll
      for (int u = 0; u < 16; ++u) { a0 += bflo(v[u]); a1 += bfhi(v[u]); }
    }
    for (; i + 3 < end; i += 4) {
      int s[4];
#pragma unroll
      for (int u = 0; u < 4; ++u) s[u] = ssrc[i + u];
      unsigned int v[4];
#pragma unroll
      for (int u = 0; u < 4; ++u)
        v[u] = *reinterpret_cast<const unsigned int*>(mc + (size_t)s[u] * H_);
#pragma unroll
      for (int u = 0; u < 4; ++u) { a0 += bflo(v[u]); a1 += bfhi(v[u]); }
    }
    for (; i < end; ++i) {
      const unsigned int v = *reinterpret_cast<const unsigned int*>(mc + (size_t)ssrc[i] * H_);
      a0 += bflo(v);  a1 += bfhi(v);
    }
    hl[row][lane] =
        (unsigned int)f2bf(fmaxf(a0, 0.f)) | ((unsigned int)f2bf(fmaxf(a1, 0.f)) << 16);
  }
  __syncthreads();

  // ---- MFMA phase (A from hl, B from Wt) ----
  const int r = lane & 15;
  const int g = lane >> 4;
  const int cb = wave * 32;
  f32x4 acc[2][2] = {};
#pragma unroll
  for (int kk = 0; kk < 4; ++kk) {
    const int koff  = kk * 32 + g * 8;        // bf16 index (for Wt)
    const int koffu = kk * 16 + g * 4;        // uint index (for hl)
    const bf16x8 a0 = *reinterpret_cast<const bf16x8*>(&hl[r][koffu]);
    const bf16x8 a1 = *reinterpret_cast<const bf16x8*>(&hl[16 + r][koffu]);
    const bf16x8 b0 = *reinterpret_cast<const bf16x8*>(Wt + (size_t)(cb + r) * H_ + koff);
    const bf16x8 b1 = *reinterpret_cast<const bf16x8*>(Wt + (size_t)(cb + 16 + r) * H_ + koff);
    acc[0][0] = __builtin_amdgcn_mfma_f32_16x16x32_bf16(a0, b0, acc[0][0], 0, 0, 0);
    acc[0][1] = __builtin_amdgcn_mfma_f32_16x16x32_bf16(a0, b1, acc[0][1], 0, 0, 0);
    acc[1][0] = __builtin_amdgcn_mfma_f32_16x16x32_bf16(a1, b0, acc[1][0], 0, 0, 0);
    acc[1][1] = __builtin_amdgcn_mfma_f32_16x16x32_bf16(a1, b1, acc[1][1], 0, 0, 0);
  }

  const float bc0 = b[cb + r];
  const float bc1 = b[cb + 16 + r];
#pragma unroll
  for (int rt = 0; rt < 2; ++rt)
#pragma unroll
    for (int ct = 0; ct < 2; ++ct) {
      const float bc = ct ? bc1 : bc0;
#pragma unroll
      for (int j = 0; j < 4; ++j)
        st[wave][rt * 16 + g * 4 + j][ct * 16 + r] = f2bf(acc[rt][ct][j] + bc);
    }
  __syncthreads();
#pragma unroll
  for (int p = 0; p < 2; ++p) {
    const int lr = p * 16 + (lane >> 2);
    const int seg = lane & 3;
    const bf16x8 v = *reinterpret_cast<const bf16x8*>(&st[wave][lr][seg * 8]);
    *reinterpret_cast<bf16x8*>(m_out + (size_t)(n0 + lr) * H_ + cb + seg * 8) = v;
  }
}

// ---------------------------------------------------------------------------
// Bucketed CSR build (line-friendly counting sort)
// ebuf entry packed: (src << 9) | dst_local
// ---------------------------------------------------------------------------
__global__ __launch_bounds__(256) void k_bhist(const int* __restrict__ ei,
                                               int* __restrict__ bcnt) {
  __shared__ int lh[NB_];
  for (int i = threadIdx.x; i < NB_; i += 256) lh[i] = 0;
  __syncthreads();
  const int gid = blockIdx.x * 256 + threadIdx.x;
  const int stride = gridDim.x * 256;
  for (int e = gid; e < E_; e += stride) atomicAdd(&lh[ei[E_ + e] >> BSH], 1);
  __syncthreads();
  for (int i = threadIdx.x; i < NB_; i += 256)
    if (lh[i]) atomicAdd(&bcnt[i], lh[i]);
}

// scan buckets -> boff/bcur; also zeroes ge (consumed by k_pool much later).
__global__ __launch_bounds__(256) void k_bscan(const int* __restrict__ bcnt,
                                               int* __restrict__ boff,
                                               int* __restrict__ bcur,
                                               float* __restrict__ ge) {
  __shared__ int s[256];
  const int t = threadIdx.x;
  s[t] = (t < NB_) ? bcnt[t] : 0;
  __syncthreads();
  for (int off = 1; off < 256; off <<= 1) {
    const int add = (t >= off) ? s[t - off] : 0;
    __syncthreads();
    s[t] += add;
    __syncthreads();
  }
  const int ex = (t == 0) ? 0 : s[t - 1];
  if (t < NB_) { boff[t] = ex; bcur[t] = ex; }
  if (t == 0) boff[NB_] = s[NB_ - 1];   // == E
  float4 z = make_float4(0.f, 0.f, 0.f, 0.f);
  float4* g4 = reinterpret_cast<float4*>(ge);
  for (int i = t; i < G_ * H_ / 4; i += 256) g4[i] = z;
}

__global__ __launch_bounds__(256) void k_bfill(const int* __restrict__ ei,
                                               int* __restrict__ bcur,
                                               unsigned int* __restrict__ ebuf) {
  __shared__ int lh[NB_], lbase[NB_];
  const int t = threadIdx.x;
  for (int i = t; i < NB_; i += 256) lh[i] = 0;
  __syncthreads();
  const int e0 = blockIdx.x * FILL_CHUNK;
  const int e1 = e0 + FILL_CHUNK;
  for (int e = e0 + t; e < e1; e += 256) atomicAdd(&lh[ei[E_ + e] >> BSH], 1);
  __syncthreads();
  for (int i = t; i < NB_; i += 256) {
    const int c = lh[i];
    lbase[i] = c ? atomicAdd(&bcur[i], c) : 0;
  }
  __syncthreads();
  for (int i = t; i < NB_; i += 256) lh[i] = 0;   // reuse as local cursor
  __syncthreads();
  for (int e = e0 + t; e < e1; e += 256) {
    const int src = ei[e], dst = ei[E_ + e];
    const int b = dst >> BSH;
    const int pos = lbase[b] + atomicAdd(&lh[b], 1);
    ebuf[pos] = ((unsigned)src << BSH) | (unsigned)(dst & (BNODES - 1));
  }
}

__global__ __launch_bounds__(256) void k_bcsr(const unsigned int* __restrict__ ebuf,
                                              const int* __restrict__ boff,
                                              int* __restrict__ rowp,
                                              int* __restrict__ ssrc) {
  __shared__ int sdeg[BNODES];
  __shared__ int scur[BNODES];
  __shared__ int part[256];
  const int b = blockIdx.x;
  const int nbase = b << BSH;
  const int ncnt = min(BNODES, N_ - nbase);
  const int ebeg = boff[b], eend = boff[b + 1];
  const int t = threadIdx.x;
  for (int i = t; i < BNODES; i += 256) { sdeg[i] = 0; scur[i] = 0; }
  __syncthreads();
  for (int e = ebeg + t; e < eend; e += 256)
    atomicAdd(&sdeg[ebuf[e] & (BNODES - 1)], 1);
  __syncthreads();
  const int i0 = 2 * t, i1 = 2 * t + 1;
  const int d0 = sdeg[i0];
  part[t] = d0 + sdeg[i1];
  __syncthreads();
  for (int off = 1; off < 256; off <<= 1) {
    const int add = (t >= off) ? part[t - off] : 0;
    __syncthreads();
    part[t] += add;
    __syncthreads();
  }
  const int ex = (t == 0) ? 0 : part[t - 1];
  sdeg[i0] = ex;
  sdeg[i1] = ex + d0;
  __syncthreads();
  for (int i = t; i < ncnt; i += 256) rowp[nbase + i] = ebeg + sdeg[i];
  if (b == NB_ - 1 && t == 0) rowp[N_] = E_;
  for (int e = ebeg + t; e < eend; e += 256) {
    const unsigned int ed = ebuf[e];
    const int ld = ed & (BNODES - 1);
    const int pos = ebeg + sdeg[ld] + atomicAdd(&scur[ld], 1);
    ssrc[pos] = (int)(ed >> BSH);
  }
}

// ---------------------------------------------------------------------------
// Standalone gather (layer 3): h[n] = relu( sum m[ssrc[e]] ), unroll-16.
// ---------------------------------------------------------------------------
__global__ __launch_bounds__(256) void k_gather(const unsigned short* __restrict__ m,
                                                const int* __restrict__ rowptr,
                                                const int* __restrict__ ssrc,
                                                unsigned short* __restrict__ h) {
  const int n = blockIdx.x * 4 + (threadIdx.x >> 6);
  const int c2 = threadIdx.x & 63;
  const int beg = rowptr[n], end = rowptr[n + 1];
  const unsigned short* mc = m + 2 * c2;
  float a0 = 0.f, a1 = 0.f;
  int i = beg;
  for (; i + 15 < end; i += 16) {
    int s[16];
#pragma unroll
    for (int u = 0; u < 16; ++u) s[u] = ssrc[i + u];
    unsigned int v[16];
#pragma unroll
    for (int u = 0; u < 16; ++u)
      v[u] = *reinterpret_cast<const unsigned int*>(mc + (size_t)s[u] * H_);
#pragma unroll
    for (int u = 0; u < 16; ++u) { a0 += bflo(v[u]); a1 += bfhi(v[u]); }
  }
  for (; i + 3 < end; i += 4) {
    int s[4];
#pragma unroll
    for (int u = 0; u < 4; ++u) s[u] = ssrc[i + u];
    unsigned int v[4];
#pragma unroll
    for (int u = 0; u < 4; ++u)
      v[u] = *reinterpret_cast<const unsigned int*>(mc + (size_t)s[u] * H_);
#pragma unroll
    for (int u = 0; u < 4; ++u) { a0 += bflo(v[u]); a1 += bfhi(v[u]); }
  }
  for (; i < end; ++i) {
    const unsigned int v = *reinterpret_cast<const unsigned int*>(mc + (size_t)ssrc[i] * H_);
    a0 += bflo(v);  a1 += bfhi(v);
  }
  const unsigned int packed =
      (unsigned int)f2bf(fmaxf(a0, 0.f)) | ((unsigned int)f2bf(fmaxf(a1, 0.f)) << 16);
  *reinterpret_cast<unsigned int*>(h + (size_t)n * H_ + 2 * c2) = packed;
}

// ---------------------------------------------------------------------------
// ge[g] += h[n] (post-relu) with batch sorted: running sum + flush.
// ---------------------------------------------------------------------------
constexpr int POOL_CHUNK = 128;
__global__ __launch_bounds__(128) void k_pool(const unsigned short* __restrict__ h,
                                              const int* __restrict__ batch,
                                              float* __restrict__ ge) {
  __shared__ int bl[POOL_CHUNK];
  const int tid = threadIdx.x;
  const int start = blockIdx.x * POOL_CHUNK;
  const int cnt = min(POOL_CHUNK, N_ - start);
  if (tid < cnt) bl[tid] = batch[start + tid];
  __syncthreads();
  float run = 0.f;
  int cur = bl[0];
  for (int i = 0; i < cnt; ++i) {
    const int bid = bl[i];
    const float v = bflo((unsigned int)h[(size_t)(start + i) * H_ + tid]);
    if (bid != cur) {
      unsafeAtomicAdd(&ge[(size_t)cur * H_ + tid], run);
      run = 0.f;
      cur = bid;
    }
    run += v;
  }
  unsafeAtomicAdd(&ge[(size_t)cur * H_ + tid], run);
}

// ---------------------------------------------------------------------------
// out = [ge @ W_mean + b_mean ; ge @ W_logvar + b_logvar]
// ---------------------------------------------------------------------------
__global__ __launch_bounds__(128) void k_out(const float* __restrict__ ge,
                                             const float* __restrict__ Wm,
                                             const float* __restrict__ bm,
                                             const float* __restrict__ Wv,
                                             const float* __restrict__ bv,
                                             float* __restrict__ out) {
  __shared__ float gl[H_];
  const int g = blockIdx.x, tid = threadIdx.x;
  gl[tid] = ge[(size_t)g * H_ + tid];
  __syncthreads();
  const bool is_mean = (tid < LAT);
  const float* W = is_mean ? Wm : Wv;
  const float* bb = is_mean ? bm : bv;
  const int c = tid & 63;
  float acc = bb[c];
#pragma unroll 8
  for (int k = 0; k < H_; ++k) acc += gl[k] * W[k * LAT + c];
  const size_t off = is_mean ? 0 : (size_t)G_ * LAT;
  out[off + (size_t)g * LAT + c] = acc;
}

// ---------------------------------------------------------------------------
extern "C" void kernel_launch(void* const* d_in, const int* in_sizes, int n_in,
                              void* d_out, int out_size, void* d_ws, size_t ws_size,
                              hipStream_t stream) {
  const float* x     = (const float*)d_in[0];
  const int*   ei    = (const int*)d_in[1];   // [2,E] int32
  const int*   batch = (const int*)d_in[2];   // [N]  int32 (sorted)
  const float* Win   = (const float*)d_in[4];
  const float* bin   = (const float*)d_in[5];
  const float* Wmsg  = (const float*)d_in[6];
  const float* bmsg  = (const float*)d_in[7];
  const float* Wmean = (const float*)d_in[8];
  const float* bmean = (const float*)d_in[9];
  const float* Wlv   = (const float*)d_in[10];
  const float* blv   = (const float*)d_in[11];
  float* out = (float*)d_out;

  // workspace layout (bytes), large-first for alignment
  char* p = (char*)d_ws;
  unsigned short* h  = (unsigned short*)p;  p += (size_t)N_ * H_ * 2;   // 25.6 MB
  unsigned short* mA = (unsigned short*)p;  p += (size_t)N_ * H_ * 2;   // 25.6 MB
  unsigned short* mB = (unsigned short*)p;  p += (size_t)N_ * H_ * 2;   // 25.6 MB
  unsigned int* ebuf = (unsigned int*)p;    p += (size_t)E_ * 4;        // 12.8 MB
  int* ssrc          = (int*)p;             p += (size_t)E_ * 4;        // 12.8 MB
  int* rowp          = (int*)p;             p += (size_t)(N_ + 1) * 4;
  unsigned short* Wt = (unsigned short*)p;  p += (size_t)L_ * H_ * H_ * 2;
  float* ge          = (float*)p;           p += (size_t)G_ * H_ * 4;
  int* bcnt          = (int*)p;             p += (size_t)NB_ * 4;
  int* boff          = (int*)p;             p += (size_t)(NB_ + 1) * 4;
  int* bcur          = (int*)p;             p += (size_t)NB_ * 4;

  // ---- fused init: weight convert (+bcnt zero) + input layer ----
  k_winit<<<WCONV_BLOCKS + N_ / 4, 256, 0, stream>>>(Wmsg, Wt, bcnt, x, Win, bin, h);

  // ---- bucketed CSR build ----
  k_bhist<<<512, 256, 0, stream>>>(ei, bcnt);
  k_bscan<<<1, 256, 0, stream>>>(bcnt, boff, bcur, ge);   // also zeroes ge
  k_bfill<<<FILL_NB, 256, 0, stream>>>(ei, bcur, ebuf);
  k_bcsr<<<NB_, 256, 0, stream>>>(ebuf, boff, rowp, ssrc);

  // ---- layer pipeline ----
  k_msg_mfma<<<N_ / 32, 256, 0, stream>>>(h, Wt, bmsg, mA);                   // msg1
  k_gm<<<N_ / 32, 256, 0, stream>>>(mA, rowp, ssrc,                           // g1+msg2
                                    Wt + (size_t)H_ * H_, bmsg + H_, mB);
  k_gm<<<N_ / 32, 256, 0, stream>>>(mB, rowp, ssrc,                           // g2+msg3
                                    Wt + (size_t)2 * H_ * H_, bmsg + 2 * H_, mA);
  k_gather<<<N_ / 4, 256, 0, stream>>>(mA, rowp, ssrc, h);                    // g3

  // ---- pooling + heads ----
  k_pool<<<(N_ + POOL_CHUNK - 1) / POOL_CHUNK, 128, 0, stream>>>(h, batch, ge);
  k_out<<<G_, 128, 0, stream>>>(ge, Wmean, bmean, Wlv, blv, out);
}